// Round 1
// baseline (2406.126 us; speedup 1.0000x reference)
//
#include <hip/hip_runtime.h>
#include <cstdint>
#include <cstddef>

#define S_   2048
#define D_   2048
#define NH_  32
#define NKV_ 8
#define HD_  64

// ---------------- GEMM: C[M][N] = A[M][K] * B[N][K]^T  (fp32 SIMT) --------
__global__ __launch_bounds__(256) void gemm_nt_f32(
    const float* __restrict__ A, const float* __restrict__ B,
    float* __restrict__ C, int M, int N, int K) {
  __shared__ float As[16][68];
  __shared__ float Bs[16][68];
  const int tid = threadIdx.x;
  const int tx = tid & 15, ty = tid >> 4;
  const int n0 = blockIdx.x * 64, m0 = blockIdx.y * 64;
  float acc[4][4] = {};
  for (int k0 = 0; k0 < K; k0 += 16) {
    const int lr = tid >> 2;          // 0..63
    const int lk = (tid & 3) * 4;     // 0,4,8,12
    float4 va = *reinterpret_cast<const float4*>(&A[(size_t)(m0 + lr) * K + k0 + lk]);
    float4 vb = *reinterpret_cast<const float4*>(&B[(size_t)(n0 + lr) * K + k0 + lk]);
    As[lk+0][lr]=va.x; As[lk+1][lr]=va.y; As[lk+2][lr]=va.z; As[lk+3][lr]=va.w;
    Bs[lk+0][lr]=vb.x; Bs[lk+1][lr]=vb.y; Bs[lk+2][lr]=vb.z; Bs[lk+3][lr]=vb.w;
    __syncthreads();
#pragma unroll
    for (int k = 0; k < 16; ++k) {
      const float4 av = *reinterpret_cast<const float4*>(&As[k][ty*4]);
      const float4 bv = *reinterpret_cast<const float4*>(&Bs[k][tx*4]);
      const float a[4] = {av.x, av.y, av.z, av.w};
      const float b[4] = {bv.x, bv.y, bv.z, bv.w};
#pragma unroll
      for (int i = 0; i < 4; ++i)
#pragma unroll
        for (int j = 0; j < 4; ++j) acc[i][j] = fmaf(a[i], b[j], acc[i][j]);
    }
    __syncthreads();
  }
#pragma unroll
  for (int i = 0; i < 4; ++i) {
    const int m = m0 + ty*4 + i;
    float4 cv = {acc[i][0], acc[i][1], acc[i][2], acc[i][3]};
    *reinterpret_cast<float4*>(&C[(size_t)m*N + n0 + tx*4]) = cv;
  }
}

// ---------------- RoPE + RMSNorm (in place), q variant --------------------
__global__ __launch_bounds__(256) void rope_norm_q(
    float* __restrict__ q, const float* __restrict__ cosT,
    const float* __restrict__ sinT, const float* __restrict__ w) {
  const int wid  = (int)((blockIdx.x * 256 + threadIdx.x) >> 6);
  const int lane = threadIdx.x & 63;
  const int s = wid >> 5;          // / NH_
  const int h = wid & 31;
  const size_t idx = (size_t)s*D_ + h*HD_ + lane;
  float val = q[idx];
  const float c  = cosT[s*32 + (lane >> 1)];
  const float sn = sinT[s*32 + (lane >> 1)];
  const float partner = __shfl_xor(val, 1);
  const float ro = (lane & 1) ? fmaf(partner, sn, val*c)
                              : fmaf(val, c, -partner*sn);
  float ssq = ro * ro;
#pragma unroll
  for (int off = 32; off >= 1; off >>= 1) ssq += __shfl_xor(ssq, off);
  const float rinv = rsqrtf(ssq * (1.0f/64.0f) + 1e-5f);
  q[idx] = ro * rinv * w[lane];
}

// ---------------- RoPE + RMSNorm (in place), k variant --------------------
__global__ __launch_bounds__(256) void rope_norm_k(
    float* __restrict__ k, const float* __restrict__ cosT,
    const float* __restrict__ sinT, const float* __restrict__ w) {
  const int wid  = (int)((blockIdx.x * 256 + threadIdx.x) >> 6);
  const int lane = threadIdx.x & 63;
  const int s   = wid >> 3;        // / NKV_
  const int kvh = wid & 7;
  const size_t idx = (size_t)s*(NKV_*HD_) + kvh*HD_ + lane;
  float val = k[idx];
  const float c  = cosT[s*32 + (lane >> 1)];
  const float sn = sinT[s*32 + (lane >> 1)];
  const float partner = __shfl_xor(val, 1);
  const float ro = (lane & 1) ? fmaf(partner, sn, val*c)
                              : fmaf(val, c, -partner*sn);
  float ssq = ro * ro;
#pragma unroll
  for (int off = 32; off >= 1; off >>= 1) ssq += __shfl_xor(ssq, off);
  const float rinv = rsqrtf(ssq * (1.0f/64.0f) + 1e-5f);
  k[idx] = ro * rinv * w[lane];
}

// ---------------- khT output: khT[h][d][s] = k_post[kvh=h/4][s][d] --------
__global__ __launch_bounds__(256) void transpose_khT(
    const float* __restrict__ kpost, float* __restrict__ khT) {
  __shared__ float tl[64][68];
  const int s0  = blockIdx.x * 64;
  const int kvh = blockIdx.y;
  const int t = threadIdx.x;
  {
    const int d0 = (t & 15) * 4;
    const int sl = t >> 4;   // 0..15
#pragma unroll
    for (int rep = 0; rep < 4; ++rep) {
      const int srow = sl + rep*16;
      float4 v = *reinterpret_cast<const float4*>(
          &kpost[(size_t)(s0 + srow)*(NKV_*HD_) + kvh*HD_ + d0]);
      tl[d0+0][srow]=v.x; tl[d0+1][srow]=v.y; tl[d0+2][srow]=v.z; tl[d0+3][srow]=v.w;
    }
  }
  __syncthreads();
  {
    const int d  = t >> 2;         // 0..63
    const int s4 = (t & 3) * 16;   // 0,16,32,48
#pragma unroll
    for (int c = 0; c < 4; ++c) {
      float4 v;
      v.x = tl[d][s4+c*4+0]; v.y = tl[d][s4+c*4+1];
      v.z = tl[d][s4+c*4+2]; v.w = tl[d][s4+c*4+3];
#pragma unroll
      for (int r = 0; r < 4; ++r) {
        *reinterpret_cast<float4*>(
            &khT[((size_t)(kvh*4 + r)*HD_ + d)*S_ + s0 + s4 + c*4]) = v;
      }
    }
  }
}

// ---------------- vh output: vh[h][s][d] = vp[s][kvh=h/4][d] --------------
__global__ __launch_bounds__(256) void copy_vh(
    const float* __restrict__ vp, float* __restrict__ vh) {
  const size_t f = (size_t)blockIdx.x * 256 + threadIdx.x;  // float4 idx, 1048576 total
  const int df = (int)(f & 15);
  const int s  = (int)((f >> 4) & 2047);
  const int h  = (int)(f >> 15);
  const float4 v = *reinterpret_cast<const float4*>(
      &vp[(size_t)s*(NKV_*HD_) + (h >> 2)*HD_ + df*4]);
  *reinterpret_cast<float4*>(&vh[f*4]) = v;
}

// ---------------- causal flash attention, fp32 ----------------------------
// block = (qtile of 16 rows, head); 4 waves, wave w owns rows w*4..w*4+3
__global__ __launch_bounds__(256) void flash_attn(
    const float* __restrict__ q, const float* __restrict__ k,
    const float* __restrict__ v, float* __restrict__ ypre) {
  __shared__ float ks[64][72];    // ks[j][d]
  __shared__ float vst[64][72];   // vst[d][j]  (v transposed)
  __shared__ float ps[16][68];    // p per local row
  const int h   = blockIdx.y;
  const int qt  = blockIdx.x;
  const int kvh = h >> 2;
  const int tid = threadIdx.x;
  const int lane = tid & 63;
  const int w = __builtin_amdgcn_readfirstlane(tid >> 6);
  const int row0 = qt * 16;
  float m_[4], l_[4], o_[4];
#pragma unroll
  for (int r = 0; r < 4; ++r) { m_[r] = -1e30f; l_[r] = 0.f; o_[r] = 0.f; }
  const int ntiles = ((row0 + 15) >> 6) + 1;
  for (int kt = 0; kt < ntiles; ++kt) {
    __syncthreads();
    {
      const int j  = tid >> 2;
      const int d0 = (tid & 3) * 16;
      const float* krow = &k[(size_t)(kt*64 + j)*(NKV_*HD_) + kvh*HD_ + d0];
      const float* vrow = &v[(size_t)(kt*64 + j)*(NKV_*HD_) + kvh*HD_ + d0];
#pragma unroll
      for (int c = 0; c < 4; ++c) {
        float4 kv = *reinterpret_cast<const float4*>(&krow[c*4]);
        ks[j][d0+c*4+0]=kv.x; ks[j][d0+c*4+1]=kv.y;
        ks[j][d0+c*4+2]=kv.z; ks[j][d0+c*4+3]=kv.w;
        float4 vv = *reinterpret_cast<const float4*>(&vrow[c*4]);
        vst[d0+c*4+0][j]=vv.x; vst[d0+c*4+1][j]=vv.y;
        vst[d0+c*4+2][j]=vv.z; vst[d0+c*4+3][j]=vv.w;
      }
    }
    __syncthreads();
    // ---- QK^T: lane = local k index j
    float sacc[4] = {0.f, 0.f, 0.f, 0.f};
    const float* qbase = &q[(size_t)(row0 + w*4)*D_ + h*HD_];
#pragma unroll
    for (int d4 = 0; d4 < 64; d4 += 4) {
      const float4 kv = *reinterpret_cast<const float4*>(&ks[lane][d4]);
#pragma unroll
      for (int r = 0; r < 4; ++r) {
        const float* qr = qbase + (size_t)r*D_;   // wave-uniform address
        sacc[r] = fmaf(qr[d4+0], kv.x, sacc[r]);
        sacc[r] = fmaf(qr[d4+1], kv.y, sacc[r]);
        sacc[r] = fmaf(qr[d4+2], kv.z, sacc[r]);
        sacc[r] = fmaf(qr[d4+3], kv.w, sacc[r]);
      }
    }
    const int kg = kt*64 + lane;
    float scl[4];
#pragma unroll
    for (int r = 0; r < 4; ++r) {
      const int grow = row0 + w*4 + r;
      const float sc = (kg <= grow) ? sacc[r]*0.125f : -1e9f;
      float mx = sc;
#pragma unroll
      for (int off = 32; off >= 1; off >>= 1) mx = fmaxf(mx, __shfl_xor(mx, off));
      const float mnew = fmaxf(m_[r], mx);
      const float esc = __expf(m_[r] - mnew);
      const float p   = __expf(sc - mnew);
      float pssum = p;
#pragma unroll
      for (int off = 32; off >= 1; off >>= 1) pssum += __shfl_xor(pssum, off);
      l_[r] = l_[r]*esc + pssum;
      m_[r] = mnew;
      scl[r] = esc;
      ps[w*4 + r][lane] = p;
    }
    __syncthreads();   // make ps visible (also keeps waves in lockstep)
    // ---- PV: lane = d
    float oa[4];
#pragma unroll
    for (int r = 0; r < 4; ++r) oa[r] = o_[r]*scl[r];
#pragma unroll
    for (int j4 = 0; j4 < 64; j4 += 4) {
      const float4 vv = *reinterpret_cast<const float4*>(&vst[lane][j4]);
#pragma unroll
      for (int r = 0; r < 4; ++r) {
        const float4 pv = *reinterpret_cast<const float4*>(&ps[w*4 + r][j4]); // broadcast
        oa[r] = fmaf(pv.x, vv.x, oa[r]);
        oa[r] = fmaf(pv.y, vv.y, oa[r]);
        oa[r] = fmaf(pv.z, vv.z, oa[r]);
        oa[r] = fmaf(pv.w, vv.w, oa[r]);
      }
    }
#pragma unroll
    for (int r = 0; r < 4; ++r) o_[r] = oa[r];
  }
#pragma unroll
  for (int r = 0; r < 4; ++r) {
    const int grow = row0 + w*4 + r;
    ypre[(size_t)grow*D_ + h*HD_ + lane] = o_[r] / l_[r];
  }
}

// --------------------------------------------------------------------------
extern "C" void kernel_launch(void* const* d_in, const int* in_sizes, int n_in,
                              void* d_out, int out_size, void* d_ws, size_t ws_size,
                              hipStream_t stream) {
  (void)in_sizes; (void)n_in; (void)out_size;
  const float* hs   = (const float*)d_in[0];
  const float* fcos = (const float*)d_in[1];
  const float* fsin = (const float*)d_in[2];
  // d_in[3] = atten_mask (pure causal; implemented directly)
  const float* wq = (const float*)d_in[4];
  const float* wk = (const float*)d_in[5];
  const float* wv = (const float*)d_in[6];
  const float* wo = (const float*)d_in[7];
  const float* qw = (const float*)d_in[8];
  const float* kw = (const float*)d_in[9];

  float* out = (float*)d_out;
  float* y   = out;                 // 2048*2048
  float* khT = out + 4194304;       // 32*64*2048
  float* vh  = out + 8388608;       // 32*2048*64

  const size_t need = (size_t)(4194304 + 1048576 + 1048576 + 4194304) * sizeof(float);
  if (ws_size < need) return;       // fail loudly (validation) rather than corrupt
  float* ws   = (float*)d_ws;
  float* qp   = ws;                 // S x 2048 (q proj, roped+normed in place)
  float* kp   = qp + 4194304;       // S x 512
  float* vp   = kp + 1048576;       // S x 512
  float* ypre = vp + 1048576;       // S x 2048 (attention out, pre-wo)

  gemm_nt_f32<<<dim3(32, 32), 256, 0, stream>>>(hs, wq, qp, 2048, 2048, 2048);
  gemm_nt_f32<<<dim3( 8, 32), 256, 0, stream>>>(hs, wk, kp, 2048,  512, 2048);
  gemm_nt_f32<<<dim3( 8, 32), 256, 0, stream>>>(hs, wv, vp, 2048,  512, 2048);

  rope_norm_q<<<16384, 256, 0, stream>>>(qp, fcos, fsin, qw);
  rope_norm_k<<< 4096, 256, 0, stream>>>(kp, fcos, fsin, kw);

  transpose_khT<<<dim3(32, 8), 256, 0, stream>>>(kp, khT);
  copy_vh<<<4096, 256, 0, stream>>>(vp, vh);

  flash_attn<<<dim3(128, 32), 256, 0, stream>>>(qp, kp, vp, ypre);

  gemm_nt_f32<<<dim3(32, 32), 256, 0, stream>>>(ypre, wo, y, 2048, 2048, 2048);
}

// Round 2
// 808.789 us; speedup vs baseline: 2.9750x; 2.9750x over previous
//
#include <hip/hip_runtime.h>
#include <cstdint>
#include <cstddef>

#define S_   2048
#define D_   2048
#define NH_  32
#define NKV_ 8
#define HD_  64

using bf16x8 = __attribute__((ext_vector_type(8))) __bf16;
using f32x4  = __attribute__((ext_vector_type(4))) float;

// ---------------- GEMM: C[M][N] = A[M][K] * B[N][K]^T  (fp32 SIMT) --------
__global__ __launch_bounds__(256) void gemm_nt_f32(
    const float* __restrict__ A, const float* __restrict__ B,
    float* __restrict__ C, int M, int N, int K) {
  __shared__ float As[16][68];
  __shared__ float Bs[16][68];
  const int tid = threadIdx.x;
  const int tx = tid & 15, ty = tid >> 4;
  const int n0 = blockIdx.x * 64, m0 = blockIdx.y * 64;
  float acc[4][4] = {};
  for (int k0 = 0; k0 < K; k0 += 16) {
    const int lr = tid >> 2;          // 0..63
    const int lk = (tid & 3) * 4;     // 0,4,8,12
    float4 va = *reinterpret_cast<const float4*>(&A[(size_t)(m0 + lr) * K + k0 + lk]);
    float4 vb = *reinterpret_cast<const float4*>(&B[(size_t)(n0 + lr) * K + k0 + lk]);
    As[lk+0][lr]=va.x; As[lk+1][lr]=va.y; As[lk+2][lr]=va.z; As[lk+3][lr]=va.w;
    Bs[lk+0][lr]=vb.x; Bs[lk+1][lr]=vb.y; Bs[lk+2][lr]=vb.z; Bs[lk+3][lr]=vb.w;
    __syncthreads();
#pragma unroll
    for (int k = 0; k < 16; ++k) {
      const float4 av = *reinterpret_cast<const float4*>(&As[k][ty*4]);
      const float4 bv = *reinterpret_cast<const float4*>(&Bs[k][tx*4]);
      const float a[4] = {av.x, av.y, av.z, av.w};
      const float b[4] = {bv.x, bv.y, bv.z, bv.w};
#pragma unroll
      for (int i = 0; i < 4; ++i)
#pragma unroll
        for (int j = 0; j < 4; ++j) acc[i][j] = fmaf(a[i], b[j], acc[i][j]);
    }
    __syncthreads();
  }
#pragma unroll
  for (int i = 0; i < 4; ++i) {
    const int m = m0 + ty*4 + i;
    float4 cv = {acc[i][0], acc[i][1], acc[i][2], acc[i][3]};
    *reinterpret_cast<float4*>(&C[(size_t)m*N + n0 + tx*4]) = cv;
  }
}

// ---------------- RoPE + RMSNorm, q variant: qp(f32) -> qbf(bf16) --------
__global__ __launch_bounds__(256) void rope_norm_q(
    const float* __restrict__ q, const float* __restrict__ cosT,
    const float* __restrict__ sinT, const float* __restrict__ w,
    __bf16* __restrict__ qbf) {
  const int wid  = (int)((blockIdx.x * 256 + threadIdx.x) >> 6);
  const int lane = threadIdx.x & 63;
  const int s = wid >> 5;          // / NH_
  const int h = wid & 31;
  const size_t idx = (size_t)s*D_ + h*HD_ + lane;
  float val = q[idx];
  const float c  = cosT[s*32 + (lane >> 1)];
  const float sn = sinT[s*32 + (lane >> 1)];
  const float partner = __shfl_xor(val, 1);
  const float ro = (lane & 1) ? fmaf(partner, sn, val*c)
                              : fmaf(val, c, -partner*sn);
  float ssq = ro * ro;
#pragma unroll
  for (int off = 32; off >= 1; off >>= 1) ssq += __shfl_xor(ssq, off);
  const float rinv = rsqrtf(ssq * (1.0f/64.0f) + 1e-5f);
  qbf[idx] = (__bf16)(ro * rinv * w[lane]);
}

// ---------------- RoPE + RMSNorm, k variant: kp in place + kbf(bf16) -----
__global__ __launch_bounds__(256) void rope_norm_k(
    float* __restrict__ k, const float* __restrict__ cosT,
    const float* __restrict__ sinT, const float* __restrict__ w,
    __bf16* __restrict__ kbf) {
  const int wid  = (int)((blockIdx.x * 256 + threadIdx.x) >> 6);
  const int lane = threadIdx.x & 63;
  const int s   = wid >> 3;        // / NKV_
  const int kvh = wid & 7;
  const size_t idx = (size_t)s*(NKV_*HD_) + kvh*HD_ + lane;
  float val = k[idx];
  const float c  = cosT[s*32 + (lane >> 1)];
  const float sn = sinT[s*32 + (lane >> 1)];
  const float partner = __shfl_xor(val, 1);
  const float ro = (lane & 1) ? fmaf(partner, sn, val*c)
                              : fmaf(val, c, -partner*sn);
  float ssq = ro * ro;
#pragma unroll
  for (int off = 32; off >= 1; off >>= 1) ssq += __shfl_xor(ssq, off);
  const float rinv = rsqrtf(ssq * (1.0f/64.0f) + 1e-5f);
  const float res = ro * rinv * w[lane];
  k[idx] = res;
  kbf[idx] = (__bf16)res;
}

// ---------------- khT output: khT[h][d][s] = k_post[kvh=h/4][s][d] --------
__global__ __launch_bounds__(256) void transpose_khT(
    const float* __restrict__ kpost, float* __restrict__ khT) {
  __shared__ float tl[64][68];
  const int s0  = blockIdx.x * 64;
  const int kvh = blockIdx.y;
  const int t = threadIdx.x;
  {
    const int d0 = (t & 15) * 4;
    const int sl = t >> 4;   // 0..15
#pragma unroll
    for (int rep = 0; rep < 4; ++rep) {
      const int srow = sl + rep*16;
      float4 v = *reinterpret_cast<const float4*>(
          &kpost[(size_t)(s0 + srow)*(NKV_*HD_) + kvh*HD_ + d0]);
      tl[d0+0][srow]=v.x; tl[d0+1][srow]=v.y; tl[d0+2][srow]=v.z; tl[d0+3][srow]=v.w;
    }
  }
  __syncthreads();
  {
    const int d  = t >> 2;         // 0..63
    const int s4 = (t & 3) * 16;   // 0,16,32,48
#pragma unroll
    for (int c = 0; c < 4; ++c) {
      float4 v;
      v.x = tl[d][s4+c*4+0]; v.y = tl[d][s4+c*4+1];
      v.z = tl[d][s4+c*4+2]; v.w = tl[d][s4+c*4+3];
#pragma unroll
      for (int r = 0; r < 4; ++r) {
        *reinterpret_cast<float4*>(
            &khT[((size_t)(kvh*4 + r)*HD_ + d)*S_ + s0 + s4 + c*4]) = v;
      }
    }
  }
}

// ---------------- vh output (f32) + vbf (bf16) ----------------------------
__global__ __launch_bounds__(256) void copy_vh(
    const float* __restrict__ vp, float* __restrict__ vh,
    __bf16* __restrict__ vbf) {
  const size_t f = (size_t)blockIdx.x * 256 + threadIdx.x;  // float4 idx, 1048576 total
  const int df = (int)(f & 15);
  const int s  = (int)((f >> 4) & 2047);
  const int h  = (int)(f >> 15);
  const size_t src = (size_t)s*(NKV_*HD_) + (h >> 2)*HD_ + df*4;
  const float4 v = *reinterpret_cast<const float4*>(&vp[src]);
  *reinterpret_cast<float4*>(&vh[f*4]) = v;
  if ((h & 3) == 0) {
    __bf16* dst = vbf + src;
    dst[0] = (__bf16)v.x; dst[1] = (__bf16)v.y;
    dst[2] = (__bf16)v.z; dst[3] = (__bf16)v.w;
  }
}

// ---------------- causal flash attention, bf16 MFMA -----------------------
// block = (64 q-rows, head); 4 waves x 16 rows. K-tiles of 64 staged in LDS.
__global__ __launch_bounds__(256) void flash_attn_mfma(
    const __bf16* __restrict__ qbf, const __bf16* __restrict__ kbf,
    const __bf16* __restrict__ vbf, float* __restrict__ ypre) {
  __shared__ __align__(16) char kld[8192];          // K tile [64 j][64 d] bf16, swizzled
  __shared__ __align__(16) char vtl[8192];          // V^T tile [64 d][64 j] bf16, swizzled
  __shared__ __align__(16) __bf16 pld[4][16][72];   // per-wave P, padded

  const int h   = blockIdx.y;
  const int qb  = blockIdx.x;
  const int kvh = h >> 2;
  const int tid = threadIdx.x;
  const int l   = tid & 63;
  const int w   = tid >> 6;
  const int l15 = l & 15;
  const int lg  = l >> 4;           // 0..3 lane group

  // ---- load Q fragments (rows qr0 + (l&15), k-halves) ----
  const int qr0 = qb*64 + w*16;
  bf16x8 qf0, qf1;
  {
    const __bf16* qrow = qbf + (size_t)(qr0 + l15)*D_ + h*HD_ + lg*8;
    qf0 = *reinterpret_cast<const bf16x8*>(qrow);
    qf1 = *reinterpret_cast<const bf16x8*>(qrow + 32);
  }

  f32x4 o_[4];
#pragma unroll
  for (int nb = 0; nb < 4; ++nb) o_[nb] = f32x4{0.f, 0.f, 0.f, 0.f};
  float m_[4] = {-1e30f, -1e30f, -1e30f, -1e30f};
  float l_[4] = {0.f, 0.f, 0.f, 0.f};

  const ushort* vbu = reinterpret_cast<const ushort*>(vbf);

  for (int kt = 0; kt <= qb; ++kt) {
    __syncthreads();
    // ---- stage K tile: thread t -> key j = t>>2, 32B chunk ----
    {
      const int j  = tid >> 2;
      const int c0 = (tid & 3) * 16;     // bf16 col
      const uint4* src = reinterpret_cast<const uint4*>(
          kbf + (size_t)(kt*64 + j)*(NKV_*HD_) + kvh*HD_ + c0);
      const uint4 lo = src[0], hi = src[1];
      const int b0 = (j*128 + c0*2)      ^ ((j & 7) << 4);
      const int b1 = (j*128 + c0*2 + 16) ^ ((j & 7) << 4);
      *reinterpret_cast<uint4*>(kld + b0) = lo;
      *reinterpret_cast<uint4*>(kld + b1) = hi;
    }
    // ---- stage V^T tile: thread t -> d = t&63, keys j0..j0+15 ----
    {
      const int d  = tid & 63;
      const int j0 = (tid >> 6) * 16;
      ushort tv[16];
#pragma unroll
      for (int jj = 0; jj < 16; ++jj)
        tv[jj] = vbu[(size_t)(kt*64 + j0 + jj)*(NKV_*HD_) + kvh*HD_ + d];
      uint4 w0, w1;
      w0.x = (uint)tv[0]  | ((uint)tv[1]  << 16);
      w0.y = (uint)tv[2]  | ((uint)tv[3]  << 16);
      w0.z = (uint)tv[4]  | ((uint)tv[5]  << 16);
      w0.w = (uint)tv[6]  | ((uint)tv[7]  << 16);
      w1.x = (uint)tv[8]  | ((uint)tv[9]  << 16);
      w1.y = (uint)tv[10] | ((uint)tv[11] << 16);
      w1.z = (uint)tv[12] | ((uint)tv[13] << 16);
      w1.w = (uint)tv[14] | ((uint)tv[15] << 16);
      const int b0 = (d*128 + j0*2)      ^ ((d & 7) << 4);
      const int b1 = (d*128 + j0*2 + 16) ^ ((d & 7) << 4);
      *reinterpret_cast<uint4*>(vtl + b0) = w0;
      *reinterpret_cast<uint4*>(vtl + b1) = w1;
    }
    __syncthreads();

    // ---- QK^T: S[16 rows][64 keys] as 4 n-blocks ----
    f32x4 s_[4];
#pragma unroll
    for (int nb = 0; nb < 4; ++nb) {
      const int row = nb*16 + l15;                  // key index in tile
      const int bc  = lg*16;                        // byte col (k-dim)
      const bf16x8 b0 = *reinterpret_cast<const bf16x8*>(
          kld + ((row*128 + bc)      ^ ((row & 7) << 4)));
      const bf16x8 b1 = *reinterpret_cast<const bf16x8*>(
          kld + ((row*128 + bc + 64) ^ ((row & 7) << 4)));
      f32x4 t = f32x4{0.f, 0.f, 0.f, 0.f};
      t = __builtin_amdgcn_mfma_f32_16x16x32_bf16(qf0, b0, t, 0, 0, 0);
      t = __builtin_amdgcn_mfma_f32_16x16x32_bf16(qf1, b1, t, 0, 0, 0);
      s_[nb] = t;
    }

    // ---- scale + causal mask (only diagonal tile needs mask) ----
    const bool diag = (kt == qb);
#pragma unroll
    for (int nb = 0; nb < 4; ++nb) {
#pragma unroll
      for (int r = 0; r < 4; ++r) {
        float sv = s_[nb][r] * 0.125f;
        if (diag) {
          const int key_loc = nb*16 + l15;
          const int row_loc = w*16 + lg*4 + r;
          if (key_loc > row_loc) sv = -1e30f;
        }
        s_[nb][r] = sv;
      }
    }

    // ---- online softmax ----
    float scl[4];
#pragma unroll
    for (int r = 0; r < 4; ++r) {
      float mx = fmaxf(fmaxf(s_[0][r], s_[1][r]), fmaxf(s_[2][r], s_[3][r]));
#pragma unroll
      for (int off = 8; off >= 1; off >>= 1) mx = fmaxf(mx, __shfl_xor(mx, off));
      const float mnew = fmaxf(m_[r], mx);
      scl[r] = __expf(m_[r] - mnew);
      m_[r] = mnew;
    }
    float rs[4] = {0.f, 0.f, 0.f, 0.f};
#pragma unroll
    for (int nb = 0; nb < 4; ++nb) {
#pragma unroll
      for (int r = 0; r < 4; ++r) {
        const float p = __expf(s_[nb][r] - m_[r]);
        s_[nb][r] = p;
        rs[r] += p;
        pld[w][lg*4 + r][nb*16 + l15] = (__bf16)p;
      }
    }
#pragma unroll
    for (int r = 0; r < 4; ++r) {
      float t = rs[r];
#pragma unroll
      for (int off = 8; off >= 1; off >>= 1) t += __shfl_xor(t, off);
      l_[r] = l_[r]*scl[r] + t;
      o_[0][r] *= scl[r]; o_[1][r] *= scl[r]; o_[2][r] *= scl[r]; o_[3][r] *= scl[r];
    }

    // ---- P fragments (A operand) from this wave's pld ----
    const bf16x8 pa0 = *reinterpret_cast<const bf16x8*>(&pld[w][l15][lg*8]);
    const bf16x8 pa1 = *reinterpret_cast<const bf16x8*>(&pld[w][l15][32 + lg*8]);

    // ---- PV: O[16 rows][64 d] as 4 n-blocks ----
#pragma unroll
    for (int nb = 0; nb < 4; ++nb) {
      const int row = nb*16 + l15;                  // d index
      const int bc  = lg*16;                        // byte col (key-dim)
      const bf16x8 v0 = *reinterpret_cast<const bf16x8*>(
          vtl + ((row*128 + bc)      ^ ((row & 7) << 4)));
      const bf16x8 v1 = *reinterpret_cast<const bf16x8*>(
          vtl + ((row*128 + bc + 64) ^ ((row & 7) << 4)));
      f32x4 t = o_[nb];
      t = __builtin_amdgcn_mfma_f32_16x16x32_bf16(pa0, v0, t, 0, 0, 0);
      t = __builtin_amdgcn_mfma_f32_16x16x32_bf16(pa1, v1, t, 0, 0, 0);
      o_[nb] = t;
    }
  }

  // ---- epilogue ----
#pragma unroll
  for (int nb = 0; nb < 4; ++nb) {
#pragma unroll
    for (int r = 0; r < 4; ++r) {
      const int row_g = qb*64 + w*16 + lg*4 + r;
      ypre[(size_t)row_g*D_ + h*HD_ + nb*16 + l15] = o_[nb][r] / l_[r];
    }
  }
}

// --------------------------------------------------------------------------
extern "C" void kernel_launch(void* const* d_in, const int* in_sizes, int n_in,
                              void* d_out, int out_size, void* d_ws, size_t ws_size,
                              hipStream_t stream) {
  (void)in_sizes; (void)n_in; (void)out_size;
  const float* hs   = (const float*)d_in[0];
  const float* fcos = (const float*)d_in[1];
  const float* fsin = (const float*)d_in[2];
  // d_in[3] = atten_mask (pure causal; implemented directly)
  const float* wq = (const float*)d_in[4];
  const float* wk = (const float*)d_in[5];
  const float* wv = (const float*)d_in[6];
  const float* wo = (const float*)d_in[7];
  const float* qw = (const float*)d_in[8];
  const float* kw = (const float*)d_in[9];

  float* out = (float*)d_out;
  float* y   = out;                 // 2048*2048
  float* khT = out + 4194304;       // 32*64*2048
  float* vh  = out + 8388608;       // 32*2048*64

  // bf16 scratch parked in the y region (dead until the final GEMM):
  __bf16* qbf = (__bf16*)y;                         // 4M bf16 = 8MB
  __bf16* kbf = (__bf16*)((char*)y + 8*1024*1024);  // 1M bf16 = 2MB
  __bf16* vbf = (__bf16*)((char*)y + 10*1024*1024); // 1M bf16 = 2MB

  const size_t need = (size_t)(4194304 + 1048576 + 1048576 + 4194304) * sizeof(float);
  if (ws_size < need) return;
  float* ws   = (float*)d_ws;
  float* qp   = ws;                 // S x 2048 (q proj)
  float* kp   = qp + 4194304;       // S x 512  (k proj, roped+normed in place)
  float* vp   = kp + 1048576;       // S x 512
  float* ypre = vp + 1048576;       // S x 2048 (attention out, pre-wo)

  gemm_nt_f32<<<dim3(32, 32), 256, 0, stream>>>(hs, wq, qp, 2048, 2048, 2048);
  gemm_nt_f32<<<dim3( 8, 32), 256, 0, stream>>>(hs, wk, kp, 2048,  512, 2048);
  gemm_nt_f32<<<dim3( 8, 32), 256, 0, stream>>>(hs, wv, vp, 2048,  512, 2048);

  rope_norm_q<<<16384, 256, 0, stream>>>(qp, fcos, fsin, qw, qbf);
  rope_norm_k<<< 4096, 256, 0, stream>>>(kp, fcos, fsin, kw, kbf);

  transpose_khT<<<dim3(32, 8), 256, 0, stream>>>(kp, khT);
  copy_vh<<<4096, 256, 0, stream>>>(vp, vh, vbf);

  flash_attn_mfma<<<dim3(32, 32), 256, 0, stream>>>(qbf, kbf, vbf, ypre);

  gemm_nt_f32<<<dim3(32, 32), 256, 0, stream>>>(ypre, wo, y, 2048, 2048, 2048);
}

// Round 3
// 242.096 us; speedup vs baseline: 9.9387x; 3.3408x over previous
//
#include <hip/hip_runtime.h>
#include <cstdint>
#include <cstddef>

#define S_   2048
#define D_   2048
#define NH_  32
#define NKV_ 8
#define HD_  64

using bf16x8 = __attribute__((ext_vector_type(8))) __bf16;
using f32x4  = __attribute__((ext_vector_type(4))) float;

#define AS_GLOBAL(p) (const __attribute__((address_space(1))) void*)(p)
#define AS_LDS(p)    (__attribute__((address_space(3))) void*)(p)

// ---------------- f32 -> bf16 bulk convert (vectorized) -------------------
__global__ __launch_bounds__(256) void cvt_f32_bf16(
    const float* __restrict__ in, __bf16* __restrict__ out, int n4) {
  const int i = blockIdx.x * 256 + threadIdx.x;
  if (i >= n4) return;
  const float4 v = reinterpret_cast<const float4*>(in)[i];
  __bf16 t[4] = {(__bf16)v.x, (__bf16)v.y, (__bf16)v.z, (__bf16)v.w};
  reinterpret_cast<uint2*>(out)[i] = *reinterpret_cast<uint2*>(t);
}

// ---------------- bf16 MFMA GEMM core: C[M][N] += A[M][K] * B[N][K]^T -----
// 128x128 tile, BK=64, 4 waves (2x2), 64x64 per wave, global_load_lds w=16,
// LDS chunk-XOR swizzle carried via pre-swizzled global source (rule #21).
__device__ __forceinline__ void gemm_tile_128(
    const __bf16* __restrict__ A, const __bf16* __restrict__ B,
    float* __restrict__ C, int K, int N, int m0, int n0) {
  __shared__ __align__(16) char ldsA[16384];
  __shared__ __align__(16) char ldsB[16384];
  const int tid = threadIdx.x;
  const int l = tid & 63;
  const int w = tid >> 6;
  const int l15 = l & 15, lg = l >> 4;
  const int wm = w >> 1, wn = w & 1;

  f32x4 acc[4][4] = {};

  // staging: thread t covers (row = i*32 + t/8, chunk = t&7); source chunk
  // pre-swizzled so LDS slot (row,c) holds global chunk c^(row&7).
  const int srow   = tid >> 3;
  const int schunk = (tid & 7) ^ (srow & 7);
  const __bf16* gA = A + (size_t)(m0 + srow) * K + schunk * 8;
  const __bf16* gB = B + (size_t)(n0 + srow) * K + schunk * 8;
  const int ldst = tid * 16;

  for (int k0 = 0; k0 < K; k0 += 64) {
    __syncthreads();
#pragma unroll
    for (int i = 0; i < 4; ++i) {
      __builtin_amdgcn_global_load_lds(AS_GLOBAL(gA + (size_t)i*32*K + k0),
                                       AS_LDS(ldsA + i*4096 + ldst), 16, 0, 0);
      __builtin_amdgcn_global_load_lds(AS_GLOBAL(gB + (size_t)i*32*K + k0),
                                       AS_LDS(ldsB + i*4096 + ldst), 16, 0, 0);
    }
    __syncthreads();   // compiler drains vmcnt(0) before barrier

    bf16x8 af[4][2], bfr[4][2];
#pragma unroll
    for (int f = 0; f < 4; ++f) {
      const int arow = wm*64 + f*16 + l15;
      const int brow = wn*64 + f*16 + l15;
#pragma unroll
      for (int ks = 0; ks < 2; ++ks) {
        af[f][ks] = *reinterpret_cast<const bf16x8*>(
            ldsA + arow*128 + (((ks*4 + lg) ^ (arow & 7)) << 4));
        bfr[f][ks] = *reinterpret_cast<const bf16x8*>(
            ldsB + brow*128 + (((ks*4 + lg) ^ (brow & 7)) << 4));
      }
    }
#pragma unroll
    for (int mf = 0; mf < 4; ++mf)
#pragma unroll
      for (int nf = 0; nf < 4; ++nf) {
        acc[mf][nf] = __builtin_amdgcn_mfma_f32_16x16x32_bf16(
            af[mf][0], bfr[nf][0], acc[mf][nf], 0, 0, 0);
        acc[mf][nf] = __builtin_amdgcn_mfma_f32_16x16x32_bf16(
            af[mf][1], bfr[nf][1], acc[mf][nf], 0, 0, 0);
      }
  }

#pragma unroll
  for (int mf = 0; mf < 4; ++mf)
#pragma unroll
    for (int nf = 0; nf < 4; ++nf)
#pragma unroll
      for (int r = 0; r < 4; ++r)
        C[(size_t)(m0 + wm*64 + mf*16 + lg*4 + r) * N + n0 + wn*64 + nf*16 + l15]
            = acc[mf][nf][r];
}

// fused Q/K/V projection: grid.x 0..15 -> wq tiles, 16..19 -> wk, 20..23 -> wv
__global__ __launch_bounds__(256) void gemm_qkv(
    const __bf16* __restrict__ hs,
    const __bf16* __restrict__ wq, const __bf16* __restrict__ wk,
    const __bf16* __restrict__ wv,
    float* __restrict__ qp, float* __restrict__ kp, float* __restrict__ vp) {
  const int bx = blockIdx.x;
  const __bf16* Bm; float* Cm; int N, n0;
  if (bx < 16)      { Bm = wq; Cm = qp; N = 2048; n0 = bx * 128; }
  else if (bx < 20) { Bm = wk; Cm = kp; N = 512;  n0 = (bx - 16) * 128; }
  else              { Bm = wv; Cm = vp; N = 512;  n0 = (bx - 20) * 128; }
  gemm_tile_128(hs, Bm, Cm, 2048, N, blockIdx.y * 128, n0);
}

__global__ __launch_bounds__(256) void gemm_wo(
    const __bf16* __restrict__ ypre, const __bf16* __restrict__ wo,
    float* __restrict__ y) {
  gemm_tile_128(ypre, wo, y, 2048, 2048, blockIdx.y * 128, blockIdx.x * 128);
}

// ---------------- RoPE + RMSNorm, q variant: qp(f32) -> qbf(bf16) --------
__global__ __launch_bounds__(256) void rope_norm_q(
    const float* __restrict__ q, const float* __restrict__ cosT,
    const float* __restrict__ sinT, const float* __restrict__ w,
    __bf16* __restrict__ qbf) {
  const int wid  = (int)((blockIdx.x * 256 + threadIdx.x) >> 6);
  const int lane = threadIdx.x & 63;
  const int s = wid >> 5;          // / NH_
  const int h = wid & 31;
  const size_t idx = (size_t)s*D_ + h*HD_ + lane;
  float val = q[idx];
  const float c  = cosT[s*32 + (lane >> 1)];
  const float sn = sinT[s*32 + (lane >> 1)];
  const float partner = __shfl_xor(val, 1);
  const float ro = (lane & 1) ? fmaf(partner, sn, val*c)
                              : fmaf(val, c, -partner*sn);
  float ssq = ro * ro;
#pragma unroll
  for (int off = 32; off >= 1; off >>= 1) ssq += __shfl_xor(ssq, off);
  const float rinv = rsqrtf(ssq * (1.0f/64.0f) + 1e-5f);
  qbf[idx] = (__bf16)(ro * rinv * w[lane]);
}

// ---------------- RoPE + RMSNorm, k variant: kp in place + kbf(bf16) -----
__global__ __launch_bounds__(256) void rope_norm_k(
    float* __restrict__ k, const float* __restrict__ cosT,
    const float* __restrict__ sinT, const float* __restrict__ w,
    __bf16* __restrict__ kbf) {
  const int wid  = (int)((blockIdx.x * 256 + threadIdx.x) >> 6);
  const int lane = threadIdx.x & 63;
  const int s   = wid >> 3;        // / NKV_
  const int kvh = wid & 7;
  const size_t idx = (size_t)s*(NKV_*HD_) + kvh*HD_ + lane;
  float val = k[idx];
  const float c  = cosT[s*32 + (lane >> 1)];
  const float sn = sinT[s*32 + (lane >> 1)];
  const float partner = __shfl_xor(val, 1);
  const float ro = (lane & 1) ? fmaf(partner, sn, val*c)
                              : fmaf(val, c, -partner*sn);
  float ssq = ro * ro;
#pragma unroll
  for (int off = 32; off >= 1; off >>= 1) ssq += __shfl_xor(ssq, off);
  const float rinv = rsqrtf(ssq * (1.0f/64.0f) + 1e-5f);
  const float res = ro * rinv * w[lane];
  k[idx] = res;
  kbf[idx] = (__bf16)res;
}

// ---------------- khT output: khT[h][d][s] = k_post[kvh=h/4][s][d] --------
__global__ __launch_bounds__(256) void transpose_khT(
    const float* __restrict__ kpost, float* __restrict__ khT) {
  __shared__ float tl[64][68];
  const int s0  = blockIdx.x * 64;
  const int kvh = blockIdx.y;
  const int t = threadIdx.x;
  {
    const int d0 = (t & 15) * 4;
    const int sl = t >> 4;   // 0..15
#pragma unroll
    for (int rep = 0; rep < 4; ++rep) {
      const int srow = sl + rep*16;
      float4 v = *reinterpret_cast<const float4*>(
          &kpost[(size_t)(s0 + srow)*(NKV_*HD_) + kvh*HD_ + d0]);
      tl[d0+0][srow]=v.x; tl[d0+1][srow]=v.y; tl[d0+2][srow]=v.z; tl[d0+3][srow]=v.w;
    }
  }
  __syncthreads();
  {
    const int d  = t >> 2;         // 0..63
    const int s4 = (t & 3) * 16;   // 0,16,32,48
#pragma unroll
    for (int c = 0; c < 4; ++c) {
      float4 v;
      v.x = tl[d][s4+c*4+0]; v.y = tl[d][s4+c*4+1];
      v.z = tl[d][s4+c*4+2]; v.w = tl[d][s4+c*4+3];
#pragma unroll
      for (int r = 0; r < 4; ++r) {
        *reinterpret_cast<float4*>(
            &khT[((size_t)(kvh*4 + r)*HD_ + d)*S_ + s0 + s4 + c*4]) = v;
      }
    }
  }
}

// ---------------- vh output (f32) + vbf (bf16) ----------------------------
__global__ __launch_bounds__(256) void copy_vh(
    const float* __restrict__ vp, float* __restrict__ vh,
    __bf16* __restrict__ vbf) {
  const size_t f = (size_t)blockIdx.x * 256 + threadIdx.x;  // float4 idx, 1048576 total
  const int df = (int)(f & 15);
  const int s  = (int)((f >> 4) & 2047);
  const int h  = (int)(f >> 15);
  const size_t src = (size_t)s*(NKV_*HD_) + (h >> 2)*HD_ + df*4;
  const float4 v = *reinterpret_cast<const float4*>(&vp[src]);
  *reinterpret_cast<float4*>(&vh[f*4]) = v;
  if ((h & 3) == 0) {
    __bf16* dst = vbf + src;
    dst[0] = (__bf16)v.x; dst[1] = (__bf16)v.y;
    dst[2] = (__bf16)v.z; dst[3] = (__bf16)v.w;
  }
}

// ---------------- causal flash attention, bf16 MFMA -----------------------
// block = (64 q-rows, head); 4 waves x 16 rows. K-tiles of 64 staged in LDS.
__global__ __launch_bounds__(256) void flash_attn_mfma(
    const __bf16* __restrict__ qbf, const __bf16* __restrict__ kbf,
    const __bf16* __restrict__ vbf, __bf16* __restrict__ ypre) {
  __shared__ __align__(16) char kld[8192];          // K tile [64 j][64 d] bf16, swizzled
  __shared__ __align__(16) char vtl[8192];          // V^T tile [64 d][64 j] bf16, swizzled
  __shared__ __align__(16) __bf16 pld[4][16][72];   // per-wave P, padded

  const int h   = blockIdx.y;
  const int qb  = blockIdx.x;
  const int kvh = h >> 2;
  const int tid = threadIdx.x;
  const int l   = tid & 63;
  const int w   = tid >> 6;
  const int l15 = l & 15;
  const int lg  = l >> 4;           // 0..3 lane group

  // ---- load Q fragments (rows qr0 + (l&15), k-halves) ----
  const int qr0 = qb*64 + w*16;
  bf16x8 qf0, qf1;
  {
    const __bf16* qrow = qbf + (size_t)(qr0 + l15)*D_ + h*HD_ + lg*8;
    qf0 = *reinterpret_cast<const bf16x8*>(qrow);
    qf1 = *reinterpret_cast<const bf16x8*>(qrow + 32);
  }

  f32x4 o_[4];
#pragma unroll
  for (int nb = 0; nb < 4; ++nb) o_[nb] = f32x4{0.f, 0.f, 0.f, 0.f};
  float m_[4] = {-1e30f, -1e30f, -1e30f, -1e30f};
  float l_[4] = {0.f, 0.f, 0.f, 0.f};

  const ushort* vbu = reinterpret_cast<const ushort*>(vbf);

  for (int kt = 0; kt <= qb; ++kt) {
    __syncthreads();
    // ---- stage K tile: thread t -> key j = t>>2, 32B chunk ----
    {
      const int j  = tid >> 2;
      const int c0 = (tid & 3) * 16;     // bf16 col
      const uint4* src = reinterpret_cast<const uint4*>(
          kbf + (size_t)(kt*64 + j)*(NKV_*HD_) + kvh*HD_ + c0);
      const uint4 lo = src[0], hi = src[1];
      const int b0 = (j*128 + c0*2)      ^ ((j & 7) << 4);
      const int b1 = (j*128 + c0*2 + 16) ^ ((j & 7) << 4);
      *reinterpret_cast<uint4*>(kld + b0) = lo;
      *reinterpret_cast<uint4*>(kld + b1) = hi;
    }
    // ---- stage V^T tile: thread t -> d = t&63, keys j0..j0+15 ----
    {
      const int d  = tid & 63;
      const int j0 = (tid >> 6) * 16;
      ushort tv[16];
#pragma unroll
      for (int jj = 0; jj < 16; ++jj)
        tv[jj] = vbu[(size_t)(kt*64 + j0 + jj)*(NKV_*HD_) + kvh*HD_ + d];
      uint4 w0, w1;
      w0.x = (uint)tv[0]  | ((uint)tv[1]  << 16);
      w0.y = (uint)tv[2]  | ((uint)tv[3]  << 16);
      w0.z = (uint)tv[4]  | ((uint)tv[5]  << 16);
      w0.w = (uint)tv[6]  | ((uint)tv[7]  << 16);
      w1.x = (uint)tv[8]  | ((uint)tv[9]  << 16);
      w1.y = (uint)tv[10] | ((uint)tv[11] << 16);
      w1.z = (uint)tv[12] | ((uint)tv[13] << 16);
      w1.w = (uint)tv[14] | ((uint)tv[15] << 16);
      const int b0 = (d*128 + j0*2)      ^ ((d & 7) << 4);
      const int b1 = (d*128 + j0*2 + 16) ^ ((d & 7) << 4);
      *reinterpret_cast<uint4*>(vtl + b0) = w0;
      *reinterpret_cast<uint4*>(vtl + b1) = w1;
    }
    __syncthreads();

    // ---- QK^T: S[16 rows][64 keys] as 4 n-blocks ----
    f32x4 s_[4];
#pragma unroll
    for (int nb = 0; nb < 4; ++nb) {
      const int row = nb*16 + l15;                  // key index in tile
      const int bc  = lg*16;                        // byte col (k-dim)
      const bf16x8 b0 = *reinterpret_cast<const bf16x8*>(
          kld + ((row*128 + bc)      ^ ((row & 7) << 4)));
      const bf16x8 b1 = *reinterpret_cast<const bf16x8*>(
          kld + ((row*128 + bc + 64) ^ ((row & 7) << 4)));
      f32x4 t = f32x4{0.f, 0.f, 0.f, 0.f};
      t = __builtin_amdgcn_mfma_f32_16x16x32_bf16(qf0, b0, t, 0, 0, 0);
      t = __builtin_amdgcn_mfma_f32_16x16x32_bf16(qf1, b1, t, 0, 0, 0);
      s_[nb] = t;
    }

    // ---- scale + causal mask (only diagonal tile needs mask) ----
    const bool diag = (kt == qb);
#pragma unroll
    for (int nb = 0; nb < 4; ++nb) {
#pragma unroll
      for (int r = 0; r < 4; ++r) {
        float sv = s_[nb][r] * 0.125f;
        if (diag) {
          const int key_loc = nb*16 + l15;
          const int row_loc = w*16 + lg*4 + r;
          if (key_loc > row_loc) sv = -1e30f;
        }
        s_[nb][r] = sv;
      }
    }

    // ---- online softmax ----
    float scl[4];
#pragma unroll
    for (int r = 0; r < 4; ++r) {
      float mx = fmaxf(fmaxf(s_[0][r], s_[1][r]), fmaxf(s_[2][r], s_[3][r]));
#pragma unroll
      for (int off = 8; off >= 1; off >>= 1) mx = fmaxf(mx, __shfl_xor(mx, off));
      const float mnew = fmaxf(m_[r], mx);
      scl[r] = __expf(m_[r] - mnew);
      m_[r] = mnew;
    }
    float rs[4] = {0.f, 0.f, 0.f, 0.f};
#pragma unroll
    for (int nb = 0; nb < 4; ++nb) {
#pragma unroll
      for (int r = 0; r < 4; ++r) {
        const float p = __expf(s_[nb][r] - m_[r]);
        s_[nb][r] = p;
        rs[r] += p;
        pld[w][lg*4 + r][nb*16 + l15] = (__bf16)p;
      }
    }
#pragma unroll
    for (int r = 0; r < 4; ++r) {
      float t = rs[r];
#pragma unroll
      for (int off = 8; off >= 1; off >>= 1) t += __shfl_xor(t, off);
      l_[r] = l_[r]*scl[r] + t;
      o_[0][r] *= scl[r]; o_[1][r] *= scl[r]; o_[2][r] *= scl[r]; o_[3][r] *= scl[r];
    }

    // ---- P fragments (A operand) from this wave's pld ----
    const bf16x8 pa0 = *reinterpret_cast<const bf16x8*>(&pld[w][l15][lg*8]);
    const bf16x8 pa1 = *reinterpret_cast<const bf16x8*>(&pld[w][l15][32 + lg*8]);

    // ---- PV: O[16 rows][64 d] as 4 n-blocks ----
#pragma unroll
    for (int nb = 0; nb < 4; ++nb) {
      const int row = nb*16 + l15;                  // d index
      const int bc  = lg*16;                        // byte col (key-dim)
      const bf16x8 v0 = *reinterpret_cast<const bf16x8*>(
          vtl + ((row*128 + bc)      ^ ((row & 7) << 4)));
      const bf16x8 v1 = *reinterpret_cast<const bf16x8*>(
          vtl + ((row*128 + bc + 64) ^ ((row & 7) << 4)));
      f32x4 t = o_[nb];
      t = __builtin_amdgcn_mfma_f32_16x16x32_bf16(pa0, v0, t, 0, 0, 0);
      t = __builtin_amdgcn_mfma_f32_16x16x32_bf16(pa1, v1, t, 0, 0, 0);
      o_[nb] = t;
    }
  }

  // ---- epilogue (bf16 — only consumed by the wo GEMM) ----
#pragma unroll
  for (int nb = 0; nb < 4; ++nb) {
#pragma unroll
    for (int r = 0; r < 4; ++r) {
      const int row_g = qb*64 + w*16 + lg*4 + r;
      ypre[(size_t)row_g*D_ + h*HD_ + nb*16 + l15] = (__bf16)(o_[nb][r] / l_[r]);
    }
  }
}

// --------------------------------------------------------------------------
extern "C" void kernel_launch(void* const* d_in, const int* in_sizes, int n_in,
                              void* d_out, int out_size, void* d_ws, size_t ws_size,
                              hipStream_t stream) {
  (void)in_sizes; (void)n_in; (void)out_size;
  const float* hs   = (const float*)d_in[0];
  const float* fcos = (const float*)d_in[1];
  const float* fsin = (const float*)d_in[2];
  // d_in[3] = atten_mask (pure causal; implemented directly)
  const float* wq = (const float*)d_in[4];
  const float* wk = (const float*)d_in[5];
  const float* wv = (const float*)d_in[6];
  const float* wo = (const float*)d_in[7];
  const float* qw = (const float*)d_in[8];
  const float* kw = (const float*)d_in[9];

  float* out = (float*)d_out;
  float* y   = out;                 // 2048*2048
  float* khT = out + 4194304;       // 32*64*2048
  float* vh  = out + 8388608;       // 32*2048*64

  // bf16 scratch parked in dead d_out regions:
  //  y region   (16MB): qbf 8MB | kbf 2MB | vbf 2MB     (dead once wo GEMM runs)
  //  khT region (16MB): hs_bf 8MB | wq_bf 8MB           (dead after QKV GEMM)
  //  vh region  (16MB): wk_bf 2MB | wv_bf 2MB           (dead after QKV GEMM)
  __bf16* qbf   = (__bf16*)y;
  __bf16* kbf   = (__bf16*)((char*)y + 8*1024*1024);
  __bf16* vbf   = (__bf16*)((char*)y + 10*1024*1024);
  __bf16* hs_bf = (__bf16*)khT;
  __bf16* wq_bf = (__bf16*)((char*)khT + 8*1024*1024);
  __bf16* wk_bf = (__bf16*)vh;
  __bf16* wv_bf = (__bf16*)((char*)vh + 2*1024*1024);

  const size_t need = (size_t)40 * 1024 * 1024;
  if (ws_size < need) return;
  char* ws = (char*)d_ws;
  float*  qp      = (float*)(ws);                    // 16MB: S x 2048 f32
  float*  kp      = (float*)(ws + 16*1024*1024);     //  4MB: S x 512 f32
  float*  vp      = (float*)(ws + 20*1024*1024);     //  4MB: S x 512 f32
  __bf16* ypre_bf = (__bf16*)(ws + 24*1024*1024);    //  8MB: S x 2048 bf16
  __bf16* wo_bf   = (__bf16*)(ws + 32*1024*1024);    //  8MB

  // convert fp32 inputs to bf16
  cvt_f32_bf16<<<4096, 256, 0, stream>>>(hs, hs_bf, 1048576);
  cvt_f32_bf16<<<4096, 256, 0, stream>>>(wq, wq_bf, 1048576);
  cvt_f32_bf16<<<1024, 256, 0, stream>>>(wk, wk_bf, 262144);
  cvt_f32_bf16<<<1024, 256, 0, stream>>>(wv, wv_bf, 262144);
  cvt_f32_bf16<<<4096, 256, 0, stream>>>(wo, wo_bf, 1048576);

  // fused Q/K/V projections (bf16 MFMA, fp32 out)
  gemm_qkv<<<dim3(24, 16), 256, 0, stream>>>(hs_bf, wq_bf, wk_bf, wv_bf, qp, kp, vp);

  rope_norm_q<<<16384, 256, 0, stream>>>(qp, fcos, fsin, qw, qbf);
  rope_norm_k<<< 4096, 256, 0, stream>>>(kp, fcos, fsin, kw, kbf);

  transpose_khT<<<dim3(32, 8), 256, 0, stream>>>(kp, khT);   // khT scratch dead now
  copy_vh<<<4096, 256, 0, stream>>>(vp, vh, vbf);            // vh scratch dead now

  flash_attn_mfma<<<dim3(32, 32), 256, 0, stream>>>(qbf, kbf, vbf, ypre_bf);

  // output projection (y region scratch dead now)
  gemm_wo<<<dim3(16, 16), 256, 0, stream>>>(ypre_bf, wo_bf, y);
}

// Round 5
// 231.215 us; speedup vs baseline: 10.4064x; 1.0471x over previous
//
#include <hip/hip_runtime.h>
#include <cstdint>
#include <cstddef>

#define S_   2048
#define D_   2048
#define NH_  32
#define NKV_ 8
#define HD_  64

using bf16x8 = __attribute__((ext_vector_type(8))) __bf16;
using f32x4  = __attribute__((ext_vector_type(4))) float;

#define AS_GLOBAL(p) (const __attribute__((address_space(1))) void*)(p)
#define AS_LDS(p)    (__attribute__((address_space(3))) void*)(p)

// ---------------- f32 -> bf16 bulk convert (vectorized) -------------------
__global__ __launch_bounds__(256) void cvt_f32_bf16(
    const float* __restrict__ in, __bf16* __restrict__ out, int n4) {
  const int i = blockIdx.x * 256 + threadIdx.x;
  if (i >= n4) return;
  const float4 v = reinterpret_cast<const float4*>(in)[i];
  __bf16 t[4] = {(__bf16)v.x, (__bf16)v.y, (__bf16)v.z, (__bf16)v.w};
  reinterpret_cast<uint2*>(out)[i] = *reinterpret_cast<uint2*>(t);
}

// ---------------- bf16 MFMA GEMM core: C[M][N] = A[M][K] * B[N][K]^T ------
// 128x128 tile, BK=64, 4 waves (2x2), 64x64 per wave, global_load_lds w=16,
// LDS chunk-XOR swizzle carried via pre-swizzled global source (rule #21).
__device__ __forceinline__ void gemm_tile_128(
    const __bf16* __restrict__ A, const __bf16* __restrict__ B,
    float* __restrict__ C, int K, int N, int m0, int n0) {
  __shared__ __align__(16) char ldsA[16384];
  __shared__ __align__(16) char ldsB[16384];
  const int tid = threadIdx.x;
  const int l = tid & 63;
  const int w = tid >> 6;
  const int l15 = l & 15, lg = l >> 4;
  const int wm = w >> 1, wn = w & 1;

  f32x4 acc[4][4] = {};

  const int srow   = tid >> 3;
  const int schunk = (tid & 7) ^ (srow & 7);
  const __bf16* gA = A + (size_t)(m0 + srow) * K + schunk * 8;
  const __bf16* gB = B + (size_t)(n0 + srow) * K + schunk * 8;
  const int ldst = tid * 16;

  for (int k0 = 0; k0 < K; k0 += 64) {
    __syncthreads();
#pragma unroll
    for (int i = 0; i < 4; ++i) {
      __builtin_amdgcn_global_load_lds(AS_GLOBAL(gA + (size_t)i*32*K + k0),
                                       AS_LDS(ldsA + i*4096 + ldst), 16, 0, 0);
      __builtin_amdgcn_global_load_lds(AS_GLOBAL(gB + (size_t)i*32*K + k0),
                                       AS_LDS(ldsB + i*4096 + ldst), 16, 0, 0);
    }
    __syncthreads();   // compiler drains vmcnt(0) before barrier

    bf16x8 af[4][2], bfr[4][2];
#pragma unroll
    for (int f = 0; f < 4; ++f) {
      const int arow = wm*64 + f*16 + l15;
      const int brow = wn*64 + f*16 + l15;
#pragma unroll
      for (int ks = 0; ks < 2; ++ks) {
        af[f][ks] = *reinterpret_cast<const bf16x8*>(
            ldsA + arow*128 + (((ks*4 + lg) ^ (arow & 7)) << 4));
        bfr[f][ks] = *reinterpret_cast<const bf16x8*>(
            ldsB + brow*128 + (((ks*4 + lg) ^ (brow & 7)) << 4));
      }
    }
#pragma unroll
    for (int mf = 0; mf < 4; ++mf)
#pragma unroll
      for (int nf = 0; nf < 4; ++nf) {
        acc[mf][nf] = __builtin_amdgcn_mfma_f32_16x16x32_bf16(
            af[mf][0], bfr[nf][0], acc[mf][nf], 0, 0, 0);
        acc[mf][nf] = __builtin_amdgcn_mfma_f32_16x16x32_bf16(
            af[mf][1], bfr[nf][1], acc[mf][nf], 0, 0, 0);
      }
  }

#pragma unroll
  for (int mf = 0; mf < 4; ++mf)
#pragma unroll
    for (int nf = 0; nf < 4; ++nf)
#pragma unroll
      for (int r = 0; r < 4; ++r)
        C[(size_t)(m0 + wm*64 + mf*16 + lg*4 + r) * N + n0 + wn*64 + nf*16 + l15]
            = acc[mf][nf][r];
}

// fused Q/K/V projection: grid.x 0..15 -> wq tiles, 16..19 -> wk, 20..23 -> wv
__global__ __launch_bounds__(256) void gemm_qkv(
    const __bf16* __restrict__ hs,
    const __bf16* __restrict__ wq, const __bf16* __restrict__ wk,
    const __bf16* __restrict__ wv,
    float* __restrict__ qp, float* __restrict__ kp, float* __restrict__ vp) {
  const int bx = blockIdx.x;
  const __bf16* Bm; float* Cm; int N, n0;
  if (bx < 16)      { Bm = wq; Cm = qp; N = 2048; n0 = bx * 128; }
  else if (bx < 20) { Bm = wk; Cm = kp; N = 512;  n0 = (bx - 16) * 128; }
  else              { Bm = wv; Cm = vp; N = 512;  n0 = (bx - 20) * 128; }
  gemm_tile_128(hs, Bm, Cm, 2048, N, blockIdx.y * 128, n0);
}

__global__ __launch_bounds__(256) void gemm_wo(
    const __bf16* __restrict__ ypre, const __bf16* __restrict__ wo,
    float* __restrict__ y) {
  gemm_tile_128(ypre, wo, y, 2048, 2048, blockIdx.y * 128, blockIdx.x * 128);
}

// ---------------- RoPE + RMSNorm, q variant: qp(f32) -> qbf(bf16, *0.125) -
__global__ __launch_bounds__(256) void rope_norm_q(
    const float* __restrict__ q, const float* __restrict__ cosT,
    const float* __restrict__ sinT, const float* __restrict__ w,
    __bf16* __restrict__ qbf) {
  const int wid  = (int)((blockIdx.x * 256 + threadIdx.x) >> 6);
  const int lane = threadIdx.x & 63;
  const int s = wid >> 5;          // / NH_
  const int h = wid & 31;
  const size_t idx = (size_t)s*D_ + h*HD_ + lane;
  float val = q[idx];
  const float c  = cosT[s*32 + (lane >> 1)];
  const float sn = sinT[s*32 + (lane >> 1)];
  const float partner = __shfl_xor(val, 1);
  const float ro = (lane & 1) ? fmaf(partner, sn, val*c)
                              : fmaf(val, c, -partner*sn);
  float ssq = ro * ro;
#pragma unroll
  for (int off = 32; off >= 1; off >>= 1) ssq += __shfl_xor(ssq, off);
  const float rinv = rsqrtf(ssq * (1.0f/64.0f) + 1e-5f);
  // fold 1/SCALE = 0.125 (exact power of two) into q for attention
  qbf[idx] = (__bf16)(ro * rinv * w[lane] * 0.125f);
}

// ---------------- RoPE + RMSNorm, k variant: kp in place + kbf(bf16) -----
__global__ __launch_bounds__(256) void rope_norm_k(
    float* __restrict__ k, const float* __restrict__ cosT,
    const float* __restrict__ sinT, const float* __restrict__ w,
    __bf16* __restrict__ kbf) {
  const int wid  = (int)((blockIdx.x * 256 + threadIdx.x) >> 6);
  const int lane = threadIdx.x & 63;
  const int s   = wid >> 3;        // / NKV_
  const int kvh = wid & 7;
  const size_t idx = (size_t)s*(NKV_*HD_) + kvh*HD_ + lane;
  float val = k[idx];
  const float c  = cosT[s*32 + (lane >> 1)];
  const float sn = sinT[s*32 + (lane >> 1)];
  const float partner = __shfl_xor(val, 1);
  const float ro = (lane & 1) ? fmaf(partner, sn, val*c)
                              : fmaf(val, c, -partner*sn);
  float ssq = ro * ro;
#pragma unroll
  for (int off = 32; off >= 1; off >>= 1) ssq += __shfl_xor(ssq, off);
  const float rinv = rsqrtf(ssq * (1.0f/64.0f) + 1e-5f);
  const float res = ro * rinv * w[lane];
  k[idx] = res;
  kbf[idx] = (__bf16)res;
}

// ---------------- khT output: khT[h][d][s] = k_post[kvh=h/4][s][d] --------
__global__ __launch_bounds__(256) void transpose_khT(
    const float* __restrict__ kpost, float* __restrict__ khT) {
  __shared__ float tl[64][68];
  const int s0  = blockIdx.x * 64;
  const int kvh = blockIdx.y;
  const int t = threadIdx.x;
  {
    const int d0 = (t & 15) * 4;
    const int sl = t >> 4;   // 0..15
#pragma unroll
    for (int rep = 0; rep < 4; ++rep) {
      const int srow = sl + rep*16;
      float4 v = *reinterpret_cast<const float4*>(
          &kpost[(size_t)(s0 + srow)*(NKV_*HD_) + kvh*HD_ + d0]);
      tl[d0+0][srow]=v.x; tl[d0+1][srow]=v.y; tl[d0+2][srow]=v.z; tl[d0+3][srow]=v.w;
    }
  }
  __syncthreads();
  {
    const int d  = t >> 2;         // 0..63
    const int s4 = (t & 3) * 16;   // 0,16,32,48
#pragma unroll
    for (int c = 0; c < 4; ++c) {
      float4 v;
      v.x = tl[d][s4+c*4+0]; v.y = tl[d][s4+c*4+1];
      v.z = tl[d][s4+c*4+2]; v.w = tl[d][s4+c*4+3];
#pragma unroll
      for (int r = 0; r < 4; ++r) {
        *reinterpret_cast<float4*>(
            &khT[((size_t)(kvh*4 + r)*HD_ + d)*S_ + s0 + s4 + c*4]) = v;
      }
    }
  }
}

// ---------------- V: vh output (f32, replicated) + vT global (bf16) -------
// block = (64 s, kvh). vh written straight from load regs; LDS only for vT.
__global__ __launch_bounds__(256) void transpose_v(
    const float* __restrict__ vp, float* __restrict__ vh,
    __bf16* __restrict__ vtbf) {
  __shared__ float tl[64][68];
  const int s0  = blockIdx.x * 64;
  const int kvh = blockIdx.y;
  const int t = threadIdx.x;
  const int srow = t >> 2, dc = (t & 3) * 16;
  const float* src = &vp[(size_t)(s0 + srow)*(NKV_*HD_) + kvh*HD_ + dc];
  float4 a = reinterpret_cast<const float4*>(src)[0];
  float4 b = reinterpret_cast<const float4*>(src)[1];
  float4 c = reinterpret_cast<const float4*>(src)[2];
  float4 d = reinterpret_cast<const float4*>(src)[3];
  *reinterpret_cast<float4*>(&tl[srow][dc])      = a;
  *reinterpret_cast<float4*>(&tl[srow][dc + 4])  = b;
  *reinterpret_cast<float4*>(&tl[srow][dc + 8])  = c;
  *reinterpret_cast<float4*>(&tl[srow][dc + 12]) = d;
#pragma unroll
  for (int r = 0; r < 4; ++r) {
    float* dst = &vh[((size_t)(kvh*4 + r)*S_ + s0 + srow)*HD_ + dc];
    reinterpret_cast<float4*>(dst)[0] = a;
    reinterpret_cast<float4*>(dst)[1] = b;
    reinterpret_cast<float4*>(dst)[2] = c;
    reinterpret_cast<float4*>(dst)[3] = d;
  }
  __syncthreads();
  const int dr = t >> 2, sc = (t & 3) * 16;
  __bf16 vals[16];
#pragma unroll
  for (int i = 0; i < 16; ++i) vals[i] = (__bf16)tl[sc + i][dr];
  // 16 bf16 = 32 bytes = TWO uint4 stores (R4 bug: only the first was written)
  uint4* dst = reinterpret_cast<uint4*>(&vtbf[((size_t)(kvh*64 + dr))*S_ + s0 + sc]);
  dst[0] = reinterpret_cast<uint4*>(vals)[0];
  dst[1] = reinterpret_cast<uint4*>(vals)[1];
}

// ---------------- causal flash attention, bf16 MFMA -----------------------
// block = (64 q-rows, head); 4 waves x 16 rows. K and V^T staged coalesced,
// register-prefetched (T14) one tile ahead.
__global__ __launch_bounds__(256) void flash_attn_mfma(
    const __bf16* __restrict__ qbf, const __bf16* __restrict__ kbf,
    const __bf16* __restrict__ vtbf, __bf16* __restrict__ ypre) {
  __shared__ __align__(16) char kld[8192];          // K tile [64 j][64 d] bf16, swizzled
  __shared__ __align__(16) char vtl[8192];          // V^T tile [64 d][64 j] bf16, swizzled
  __shared__ __align__(16) __bf16 pld[4][16][72];   // per-wave P, padded

  const int h   = blockIdx.y;
  const int qb  = blockIdx.x;
  const int kvh = h >> 2;
  const int tid = threadIdx.x;
  const int l   = tid & 63;
  const int w   = tid >> 6;
  const int l15 = l & 15;
  const int lg  = l >> 4;           // 0..3 lane group

  // staging geometry: thread t -> row j = t>>2, 32B chunk (t&3)
  const int j  = tid >> 2;
  const int c0 = (tid & 3) * 16;    // bf16 col
  const int b0 = (j*128 + c0*2)      ^ ((j & 7) << 4);
  const int b1 = (j*128 + c0*2 + 16) ^ ((j & 7) << 4);
  const __bf16* ksrc = kbf  + (size_t)j*(NKV_*HD_) + kvh*HD_ + c0;
  const __bf16* vsrc = vtbf + (size_t)(kvh*64 + j)*S_ + c0;

  // ---- load Q fragments (rows qr0 + (l&15), k-halves) ----
  const int qr0 = qb*64 + w*16;
  bf16x8 qf0, qf1;
  {
    const __bf16* qrow = qbf + (size_t)(qr0 + l15)*D_ + h*HD_ + lg*8;
    qf0 = *reinterpret_cast<const bf16x8*>(qrow);
    qf1 = *reinterpret_cast<const bf16x8*>(qrow + 32);
  }

  f32x4 o_[4];
#pragma unroll
  for (int nb = 0; nb < 4; ++nb) o_[nb] = f32x4{0.f, 0.f, 0.f, 0.f};
  float m_[4] = {-1e30f, -1e30f, -1e30f, -1e30f};
  float l_[4] = {0.f, 0.f, 0.f, 0.f};

  // prologue: prefetch tile 0
  uint4 kr0 = reinterpret_cast<const uint4*>(ksrc)[0];
  uint4 kr1 = reinterpret_cast<const uint4*>(ksrc + 8)[0];
  uint4 vr0 = reinterpret_cast<const uint4*>(vsrc)[0];
  uint4 vr1 = reinterpret_cast<const uint4*>(vsrc + 8)[0];

  for (int kt = 0; kt <= qb; ++kt) {
    __syncthreads();     // all waves done reading previous tile's LDS
    *reinterpret_cast<uint4*>(kld + b0) = kr0;
    *reinterpret_cast<uint4*>(kld + b1) = kr1;
    *reinterpret_cast<uint4*>(vtl + b0) = vr0;
    *reinterpret_cast<uint4*>(vtl + b1) = vr1;
    __syncthreads();

    // issue next tile's loads; they drain under this tile's compute (T14)
    if (kt < qb) {
      const __bf16* kn = ksrc + (size_t)(kt + 1)*64*(NKV_*HD_);
      const __bf16* vn = vsrc + (size_t)(kt + 1)*64;
      kr0 = reinterpret_cast<const uint4*>(kn)[0];
      kr1 = reinterpret_cast<const uint4*>(kn + 8)[0];
      vr0 = reinterpret_cast<const uint4*>(vn)[0];
      vr1 = reinterpret_cast<const uint4*>(vn + 8)[0];
    }

    // ---- QK^T: S[16 rows][64 keys] as 4 n-blocks (q pre-scaled) ----
    f32x4 s_[4];
#pragma unroll
    for (int nb = 0; nb < 4; ++nb) {
      const int row = nb*16 + l15;                  // key index in tile
      const int bc  = lg*16;                        // byte col (k-dim)
      const bf16x8 kb0 = *reinterpret_cast<const bf16x8*>(
          kld + ((row*128 + bc)      ^ ((row & 7) << 4)));
      const bf16x8 kb1 = *reinterpret_cast<const bf16x8*>(
          kld + ((row*128 + bc + 64) ^ ((row & 7) << 4)));
      f32x4 t = f32x4{0.f, 0.f, 0.f, 0.f};
      t = __builtin_amdgcn_mfma_f32_16x16x32_bf16(qf0, kb0, t, 0, 0, 0);
      t = __builtin_amdgcn_mfma_f32_16x16x32_bf16(qf1, kb1, t, 0, 0, 0);
      s_[nb] = t;
    }

    // ---- causal mask (diagonal tile only) ----
    if (kt == qb) {
#pragma unroll
      for (int nb = 0; nb < 4; ++nb) {
#pragma unroll
        for (int r = 0; r < 4; ++r) {
          const int key_loc = nb*16 + l15;
          const int row_loc = w*16 + lg*4 + r;
          if (key_loc > row_loc) s_[nb][r] = -1e30f;
        }
      }
    }

    // ---- online softmax ----
    float scl[4];
#pragma unroll
    for (int r = 0; r < 4; ++r) {
      float mx = fmaxf(fmaxf(s_[0][r], s_[1][r]), fmaxf(s_[2][r], s_[3][r]));
#pragma unroll
      for (int off = 8; off >= 1; off >>= 1) mx = fmaxf(mx, __shfl_xor(mx, off));
      const float mnew = fmaxf(m_[r], mx);
      scl[r] = __expf(m_[r] - mnew);
      m_[r] = mnew;
    }
    float rs[4] = {0.f, 0.f, 0.f, 0.f};
#pragma unroll
    for (int nb = 0; nb < 4; ++nb) {
#pragma unroll
      for (int r = 0; r < 4; ++r) {
        const float p = __expf(s_[nb][r] - m_[r]);
        rs[r] += p;
        pld[w][lg*4 + r][nb*16 + l15] = (__bf16)p;
      }
    }
#pragma unroll
    for (int r = 0; r < 4; ++r) {
      float t = rs[r];
#pragma unroll
      for (int off = 8; off >= 1; off >>= 1) t += __shfl_xor(t, off);
      l_[r] = l_[r]*scl[r] + t;
      o_[0][r] *= scl[r]; o_[1][r] *= scl[r]; o_[2][r] *= scl[r]; o_[3][r] *= scl[r];
    }

    // ---- P fragments (per-wave buffer; lgkmcnt orders write->read) ----
    const bf16x8 pa0 = *reinterpret_cast<const bf16x8*>(&pld[w][l15][lg*8]);
    const bf16x8 pa1 = *reinterpret_cast<const bf16x8*>(&pld[w][l15][32 + lg*8]);

    // ---- PV: O[16 rows][64 d] as 4 n-blocks ----
#pragma unroll
    for (int nb = 0; nb < 4; ++nb) {
      const int row = nb*16 + l15;                  // d index
      const int bc  = lg*16;                        // byte col (key-dim)
      const bf16x8 v0 = *reinterpret_cast<const bf16x8*>(
          vtl + ((row*128 + bc)      ^ ((row & 7) << 4)));
      const bf16x8 v1 = *reinterpret_cast<const bf16x8*>(
          vtl + ((row*128 + bc + 64) ^ ((row & 7) << 4)));
      f32x4 t = o_[nb];
      t = __builtin_amdgcn_mfma_f32_16x16x32_bf16(pa0, v0, t, 0, 0, 0);
      t = __builtin_amdgcn_mfma_f32_16x16x32_bf16(pa1, v1, t, 0, 0, 0);
      o_[nb] = t;
    }
  }

  // ---- epilogue (bf16 — only consumed by the wo GEMM) ----
#pragma unroll
  for (int nb = 0; nb < 4; ++nb) {
#pragma unroll
    for (int r = 0; r < 4; ++r) {
      const int row_g = qb*64 + w*16 + lg*4 + r;
      ypre[(size_t)row_g*D_ + h*HD_ + nb*16 + l15] = (__bf16)(o_[nb][r] / l_[r]);
    }
  }
}

// --------------------------------------------------------------------------
extern "C" void kernel_launch(void* const* d_in, const int* in_sizes, int n_in,
                              void* d_out, int out_size, void* d_ws, size_t ws_size,
                              hipStream_t stream) {
  (void)in_sizes; (void)n_in; (void)out_size;
  const float* hs   = (const float*)d_in[0];
  const float* fcos = (const float*)d_in[1];
  const float* fsin = (const float*)d_in[2];
  // d_in[3] = atten_mask (pure causal; implemented directly)
  const float* wq = (const float*)d_in[4];
  const float* wk = (const float*)d_in[5];
  const float* wv = (const float*)d_in[6];
  const float* wo = (const float*)d_in[7];
  const float* qw = (const float*)d_in[8];
  const float* kw = (const float*)d_in[9];

  float* out = (float*)d_out;
  float* y   = out;                 // 2048*2048
  float* khT = out + 4194304;       // 32*64*2048
  float* vh  = out + 8388608;       // 32*2048*64

  // bf16 scratch parked in dead d_out regions:
  //  y region   (16MB): qbf 8MB | kbf 2MB | vtbf 2MB    (dead once wo GEMM runs)
  //  khT region (16MB): hs_bf 8MB | wq_bf 8MB           (dead after QKV GEMM)
  //  vh region  (16MB): wk_bf 2MB | wv_bf 2MB           (dead after QKV GEMM)
  __bf16* qbf   = (__bf16*)y;
  __bf16* kbf   = (__bf16*)((char*)y + 8*1024*1024);
  __bf16* vtbf  = (__bf16*)((char*)y + 10*1024*1024);
  __bf16* hs_bf = (__bf16*)khT;
  __bf16* wq_bf = (__bf16*)((char*)khT + 8*1024*1024);
  __bf16* wk_bf = (__bf16*)vh;
  __bf16* wv_bf = (__bf16*)((char*)vh + 2*1024*1024);

  const size_t need = (size_t)40 * 1024 * 1024;
  if (ws_size < need) return;
  char* ws = (char*)d_ws;
  float*  qp      = (float*)(ws);                    // 16MB: S x 2048 f32
  float*  kp      = (float*)(ws + 16*1024*1024);     //  4MB: S x 512 f32
  float*  vp      = (float*)(ws + 20*1024*1024);     //  4MB: S x 512 f32
  __bf16* ypre_bf = (__bf16*)(ws + 24*1024*1024);    //  8MB: S x 2048 bf16
  __bf16* wo_bf   = (__bf16*)(ws + 32*1024*1024);    //  8MB

  // convert fp32 inputs to bf16
  cvt_f32_bf16<<<4096, 256, 0, stream>>>(hs, hs_bf, 1048576);
  cvt_f32_bf16<<<4096, 256, 0, stream>>>(wq, wq_bf, 1048576);
  cvt_f32_bf16<<<1024, 256, 0, stream>>>(wk, wk_bf, 262144);
  cvt_f32_bf16<<<1024, 256, 0, stream>>>(wv, wv_bf, 262144);
  cvt_f32_bf16<<<4096, 256, 0, stream>>>(wo, wo_bf, 1048576);

  // fused Q/K/V projections (bf16 MFMA, fp32 out)
  gemm_qkv<<<dim3(24, 16), 256, 0, stream>>>(hs_bf, wq_bf, wk_bf, wv_bf, qp, kp, vp);

  rope_norm_q<<<16384, 256, 0, stream>>>(qp, fcos, fsin, qw, qbf);
  rope_norm_k<<< 4096, 256, 0, stream>>>(kp, fcos, fsin, kw, kbf);

  transpose_khT<<<dim3(32, 8), 256, 0, stream>>>(kp, khT);   // khT scratch dead now
  transpose_v<<<dim3(32, 8), 256, 0, stream>>>(vp, vh, vtbf);// vh scratch dead now

  flash_attn_mfma<<<dim3(32, 32), 256, 0, stream>>>(qbf, kbf, vtbf, ypre_bf);

  // output projection (y region scratch dead now)
  gemm_wo<<<dim3(16, 16), 256, 0, stream>>>(ypre_bf, wo_bf, y);
}

// Round 6
// 193.987 us; speedup vs baseline: 12.4036x; 1.1919x over previous
//
#include <hip/hip_runtime.h>
#include <cstdint>
#include <cstddef>

#define S_   2048
#define D_   2048
#define NH_  32
#define NKV_ 8
#define HD_  64

using bf16x8 = __attribute__((ext_vector_type(8))) __bf16;
using f32x4  = __attribute__((ext_vector_type(4))) float;

#define AS_GLOBAL(p) (const __attribute__((address_space(1))) void*)(p)
#define AS_LDS(p)    (__attribute__((address_space(3))) void*)(p)

// ---------------- f32 -> bf16 bulk convert (vectorized) -------------------
__global__ __launch_bounds__(256) void cvt_f32_bf16(
    const float* __restrict__ in, __bf16* __restrict__ out, int n4) {
  const int i = blockIdx.x * 256 + threadIdx.x;
  if (i >= n4) return;
  const float4 v = reinterpret_cast<const float4*>(in)[i];
  __bf16 t[4] = {(__bf16)v.x, (__bf16)v.y, (__bf16)v.z, (__bf16)v.w};
  reinterpret_cast<uint2*>(out)[i] = *reinterpret_cast<uint2*>(t);
}

// ---------------- bf16 MFMA GEMM core: C[M][N] = A[M][K] * B[N][K]^T ------
// 128x128 tile, BK=64, 4 waves (2x2), 64x64 per wave, global_load_lds w=16,
// LDS chunk-XOR swizzle carried via pre-swizzled global source (rule #21).
__device__ __forceinline__ void gemm_tile_128(
    const __bf16* __restrict__ A, const __bf16* __restrict__ B,
    float* __restrict__ C, int K, int N, int m0, int n0) {
  __shared__ __align__(16) char ldsA[16384];
  __shared__ __align__(16) char ldsB[16384];
  const int tid = threadIdx.x;
  const int l = tid & 63;
  const int w = tid >> 6;
  const int l15 = l & 15, lg = l >> 4;
  const int wm = w >> 1, wn = w & 1;

  f32x4 acc[4][4] = {};

  const int srow   = tid >> 3;
  const int schunk = (tid & 7) ^ (srow & 7);
  const __bf16* gA = A + (size_t)(m0 + srow) * K + schunk * 8;
  const __bf16* gB = B + (size_t)(n0 + srow) * K + schunk * 8;
  const int ldst = tid * 16;

  for (int k0 = 0; k0 < K; k0 += 64) {
    __syncthreads();
#pragma unroll
    for (int i = 0; i < 4; ++i) {
      __builtin_amdgcn_global_load_lds(AS_GLOBAL(gA + (size_t)i*32*K + k0),
                                       AS_LDS(ldsA + i*4096 + ldst), 16, 0, 0);
      __builtin_amdgcn_global_load_lds(AS_GLOBAL(gB + (size_t)i*32*K + k0),
                                       AS_LDS(ldsB + i*4096 + ldst), 16, 0, 0);
    }
    __syncthreads();   // compiler drains vmcnt(0) before barrier

    bf16x8 af[4][2], bfr[4][2];
#pragma unroll
    for (int f = 0; f < 4; ++f) {
      const int arow = wm*64 + f*16 + l15;
      const int brow = wn*64 + f*16 + l15;
#pragma unroll
      for (int ks = 0; ks < 2; ++ks) {
        af[f][ks] = *reinterpret_cast<const bf16x8*>(
            ldsA + arow*128 + (((ks*4 + lg) ^ (arow & 7)) << 4));
        bfr[f][ks] = *reinterpret_cast<const bf16x8*>(
            ldsB + brow*128 + (((ks*4 + lg) ^ (brow & 7)) << 4));
      }
    }
#pragma unroll
    for (int mf = 0; mf < 4; ++mf)
#pragma unroll
      for (int nf = 0; nf < 4; ++nf) {
        acc[mf][nf] = __builtin_amdgcn_mfma_f32_16x16x32_bf16(
            af[mf][0], bfr[nf][0], acc[mf][nf], 0, 0, 0);
        acc[mf][nf] = __builtin_amdgcn_mfma_f32_16x16x32_bf16(
            af[mf][1], bfr[nf][1], acc[mf][nf], 0, 0, 0);
      }
  }

#pragma unroll
  for (int mf = 0; mf < 4; ++mf)
#pragma unroll
    for (int nf = 0; nf < 4; ++nf)
#pragma unroll
      for (int r = 0; r < 4; ++r)
        C[(size_t)(m0 + wm*64 + mf*16 + lg*4 + r) * N + n0 + wn*64 + nf*16 + l15]
            = acc[mf][nf][r];
}

// fused Q/K/V projection: grid.x 0..15 -> wq tiles, 16..19 -> wk, 20..23 -> wv
__global__ __launch_bounds__(256) void gemm_qkv(
    const __bf16* __restrict__ hs,
    const __bf16* __restrict__ wq, const __bf16* __restrict__ wk,
    const __bf16* __restrict__ wv,
    float* __restrict__ qp, float* __restrict__ kp, float* __restrict__ vp) {
  const int bx = blockIdx.x;
  const __bf16* Bm; float* Cm; int N, n0;
  if (bx < 16)      { Bm = wq; Cm = qp; N = 2048; n0 = bx * 128; }
  else if (bx < 20) { Bm = wk; Cm = kp; N = 512;  n0 = (bx - 16) * 128; }
  else              { Bm = wv; Cm = vp; N = 512;  n0 = (bx - 20) * 128; }
  gemm_tile_128(hs, Bm, Cm, 2048, N, blockIdx.y * 128, n0);
}

__global__ __launch_bounds__(256) void gemm_wo(
    const __bf16* __restrict__ ypre, const __bf16* __restrict__ wo,
    float* __restrict__ y) {
  gemm_tile_128(ypre, wo, y, 2048, 2048, blockIdx.y * 128, blockIdx.x * 128);
}

// ---------------- RoPE + RMSNorm, q variant: qp(f32) -> qbf(bf16, *0.125) -
__global__ __launch_bounds__(256) void rope_norm_q(
    const float* __restrict__ q, const float* __restrict__ cosT,
    const float* __restrict__ sinT, const float* __restrict__ w,
    __bf16* __restrict__ qbf) {
  const int wid  = (int)((blockIdx.x * 256 + threadIdx.x) >> 6);
  const int lane = threadIdx.x & 63;
  const int s = wid >> 5;          // / NH_
  const int h = wid & 31;
  const size_t idx = (size_t)s*D_ + h*HD_ + lane;
  float val = q[idx];
  const float c  = cosT[s*32 + (lane >> 1)];
  const float sn = sinT[s*32 + (lane >> 1)];
  const float partner = __shfl_xor(val, 1);
  const float ro = (lane & 1) ? fmaf(partner, sn, val*c)
                              : fmaf(val, c, -partner*sn);
  float ssq = ro * ro;
#pragma unroll
  for (int off = 32; off >= 1; off >>= 1) ssq += __shfl_xor(ssq, off);
  const float rinv = rsqrtf(ssq * (1.0f/64.0f) + 1e-5f);
  // fold 1/SCALE = 0.125 (exact power of two) into q for attention
  qbf[idx] = (__bf16)(ro * rinv * w[lane] * 0.125f);
}

// ---------------- RoPE + RMSNorm, k variant: kp in place + kbf(bf16) -----
__global__ __launch_bounds__(256) void rope_norm_k(
    float* __restrict__ k, const float* __restrict__ cosT,
    const float* __restrict__ sinT, const float* __restrict__ w,
    __bf16* __restrict__ kbf) {
  const int wid  = (int)((blockIdx.x * 256 + threadIdx.x) >> 6);
  const int lane = threadIdx.x & 63;
  const int s   = wid >> 3;        // / NKV_
  const int kvh = wid & 7;
  const size_t idx = (size_t)s*(NKV_*HD_) + kvh*HD_ + lane;
  float val = k[idx];
  const float c  = cosT[s*32 + (lane >> 1)];
  const float sn = sinT[s*32 + (lane >> 1)];
  const float partner = __shfl_xor(val, 1);
  const float ro = (lane & 1) ? fmaf(partner, sn, val*c)
                              : fmaf(val, c, -partner*sn);
  float ssq = ro * ro;
#pragma unroll
  for (int off = 32; off >= 1; off >>= 1) ssq += __shfl_xor(ssq, off);
  const float rinv = rsqrtf(ssq * (1.0f/64.0f) + 1e-5f);
  const float res = ro * rinv * w[lane];
  k[idx] = res;
  kbf[idx] = (__bf16)res;
}

// ---------------- khT output: khT[h][d][s] = k_post[kvh=h/4][s][d] --------
__global__ __launch_bounds__(256) void transpose_khT(
    const float* __restrict__ kpost, float* __restrict__ khT) {
  __shared__ float tl[64][68];
  const int s0  = blockIdx.x * 64;
  const int kvh = blockIdx.y;
  const int t = threadIdx.x;
  {
    const int d0 = (t & 15) * 4;
    const int sl = t >> 4;   // 0..15
#pragma unroll
    for (int rep = 0; rep < 4; ++rep) {
      const int srow = sl + rep*16;
      float4 v = *reinterpret_cast<const float4*>(
          &kpost[(size_t)(s0 + srow)*(NKV_*HD_) + kvh*HD_ + d0]);
      tl[d0+0][srow]=v.x; tl[d0+1][srow]=v.y; tl[d0+2][srow]=v.z; tl[d0+3][srow]=v.w;
    }
  }
  __syncthreads();
  {
    const int d  = t >> 2;         // 0..63
    const int s4 = (t & 3) * 16;   // 0,16,32,48
#pragma unroll
    for (int c = 0; c < 4; ++c) {
      float4 v;
      v.x = tl[d][s4+c*4+0]; v.y = tl[d][s4+c*4+1];
      v.z = tl[d][s4+c*4+2]; v.w = tl[d][s4+c*4+3];
#pragma unroll
      for (int r = 0; r < 4; ++r) {
        *reinterpret_cast<float4*>(
            &khT[((size_t)(kvh*4 + r)*HD_ + d)*S_ + s0 + s4 + c*4]) = v;
      }
    }
  }
}

// ---------------- V: vh output (f32, replicated) + vT global (bf16) -------
__global__ __launch_bounds__(256) void transpose_v(
    const float* __restrict__ vp, float* __restrict__ vh,
    __bf16* __restrict__ vtbf) {
  __shared__ float tl[64][68];
  const int s0  = blockIdx.x * 64;
  const int kvh = blockIdx.y;
  const int t = threadIdx.x;
  const int srow = t >> 2, dc = (t & 3) * 16;
  const float* src = &vp[(size_t)(s0 + srow)*(NKV_*HD_) + kvh*HD_ + dc];
  float4 a = reinterpret_cast<const float4*>(src)[0];
  float4 b = reinterpret_cast<const float4*>(src)[1];
  float4 c = reinterpret_cast<const float4*>(src)[2];
  float4 d = reinterpret_cast<const float4*>(src)[3];
  *reinterpret_cast<float4*>(&tl[srow][dc])      = a;
  *reinterpret_cast<float4*>(&tl[srow][dc + 4])  = b;
  *reinterpret_cast<float4*>(&tl[srow][dc + 8])  = c;
  *reinterpret_cast<float4*>(&tl[srow][dc + 12]) = d;
#pragma unroll
  for (int r = 0; r < 4; ++r) {
    float* dst = &vh[((size_t)(kvh*4 + r)*S_ + s0 + srow)*HD_ + dc];
    reinterpret_cast<float4*>(dst)[0] = a;
    reinterpret_cast<float4*>(dst)[1] = b;
    reinterpret_cast<float4*>(dst)[2] = c;
    reinterpret_cast<float4*>(dst)[3] = d;
  }
  __syncthreads();
  const int dr = t >> 2, sc = (t & 3) * 16;
  __bf16 vals[16];
#pragma unroll
  for (int i = 0; i < 16; ++i) vals[i] = (__bf16)tl[sc + i][dr];
  uint4* dst = reinterpret_cast<uint4*>(&vtbf[((size_t)(kvh*64 + dr))*S_ + s0 + sc]);
  dst[0] = reinterpret_cast<uint4*>(vals)[0];
  dst[1] = reinterpret_cast<uint4*>(vals)[1];
}

// ---------------- flash attention helpers --------------------------------
__device__ __forceinline__ void qk_tile(
    const char* kld, bf16x8 qf0, bf16x8 qf1, f32x4 (&s_)[4],
    int l15, int lg) {
#pragma unroll
  for (int nb = 0; nb < 4; ++nb) {
    const int row = nb*16 + l15;
    const int bc  = lg*16;
    const bf16x8 kb0 = *reinterpret_cast<const bf16x8*>(
        kld + ((row*128 + bc)      ^ ((row & 7) << 4)));
    const bf16x8 kb1 = *reinterpret_cast<const bf16x8*>(
        kld + ((row*128 + bc + 64) ^ ((row & 7) << 4)));
    f32x4 t = f32x4{0.f, 0.f, 0.f, 0.f};
    t = __builtin_amdgcn_mfma_f32_16x16x32_bf16(qf0, kb0, t, 0, 0, 0);
    t = __builtin_amdgcn_mfma_f32_16x16x32_bf16(qf1, kb1, t, 0, 0, 0);
    s_[nb] = t;
  }
}

__device__ __forceinline__ void softmax_pv(
    f32x4 (&s_)[4], float (&m_)[4], float (&l_)[4], f32x4 (&o_)[4],
    __bf16 (*pldw)[72], const char* vtl, int l15, int lg) {
  float scl[4];
#pragma unroll
  for (int r = 0; r < 4; ++r) {
    float mx = fmaxf(fmaxf(s_[0][r], s_[1][r]), fmaxf(s_[2][r], s_[3][r]));
#pragma unroll
    for (int off = 8; off >= 1; off >>= 1) mx = fmaxf(mx, __shfl_xor(mx, off));
    const float mnew = fmaxf(m_[r], mx);
    scl[r] = __expf(m_[r] - mnew);
    m_[r] = mnew;
  }
  float rs[4] = {0.f, 0.f, 0.f, 0.f};
#pragma unroll
  for (int nb = 0; nb < 4; ++nb) {
#pragma unroll
    for (int r = 0; r < 4; ++r) {
      const float p = __expf(s_[nb][r] - m_[r]);
      rs[r] += p;
      pldw[lg*4 + r][nb*16 + l15] = (__bf16)p;
    }
  }
#pragma unroll
  for (int r = 0; r < 4; ++r) {
    float t = rs[r];
#pragma unroll
    for (int off = 8; off >= 1; off >>= 1) t += __shfl_xor(t, off);
    l_[r] = l_[r]*scl[r] + t;
    o_[0][r] *= scl[r]; o_[1][r] *= scl[r]; o_[2][r] *= scl[r]; o_[3][r] *= scl[r];
  }
  const bf16x8 pa0 = *reinterpret_cast<const bf16x8*>(&pldw[l15][lg*8]);
  const bf16x8 pa1 = *reinterpret_cast<const bf16x8*>(&pldw[l15][32 + lg*8]);
#pragma unroll
  for (int nb = 0; nb < 4; ++nb) {
    const int row = nb*16 + l15;
    const int bc  = lg*16;
    const bf16x8 v0 = *reinterpret_cast<const bf16x8*>(
        vtl + ((row*128 + bc)      ^ ((row & 7) << 4)));
    const bf16x8 v1 = *reinterpret_cast<const bf16x8*>(
        vtl + ((row*128 + bc + 64) ^ ((row & 7) << 4)));
    f32x4 t = o_[nb];
    t = __builtin_amdgcn_mfma_f32_16x16x32_bf16(pa0, v0, t, 0, 0, 0);
    t = __builtin_amdgcn_mfma_f32_16x16x32_bf16(pa1, v1, t, 0, 0, 0);
    o_[nb] = t;
  }
}

// ---------------- causal flash attention, bf16 MFMA, paired q-tiles -------
// block = (pair i, head): q-tile A = i, q-tile B = 31-i. Every block does
// exactly 2(i+1) + (31-2i) = 33 compute-tile units -> perfect load balance.
// Staged K/V tiles shared between A and B (staging cut ~26%).
__global__ __launch_bounds__(256) void flash_attn_mfma(
    const __bf16* __restrict__ qbf, const __bf16* __restrict__ kbf,
    const __bf16* __restrict__ vtbf, __bf16* __restrict__ ypre) {
  __shared__ __align__(16) char kld[8192];          // K tile [64 j][64 d] bf16, swizzled
  __shared__ __align__(16) char vtl[8192];          // V^T tile [64 d][64 j] bf16, swizzled
  __shared__ __align__(16) __bf16 pld[4][16][72];   // per-wave P, padded (reused A/B)

  const int h   = blockIdx.y;
  const int pi  = blockIdx.x;       // 0..15
  const int qbA = pi, qbB = 31 - pi;
  const int nkt = qbB;              // kt = 0..nkt
  const int kvh = h >> 2;
  const int tid = threadIdx.x;
  const int l   = tid & 63;
  const int w   = tid >> 6;
  const int l15 = l & 15;
  const int lg  = l >> 4;

  // staging geometry: thread t -> row j = t>>2, 32B chunk (t&3)
  const int j  = tid >> 2;
  const int c0 = (tid & 3) * 16;
  const int b0 = (j*128 + c0*2)      ^ ((j & 7) << 4);
  const int b1 = (j*128 + c0*2 + 16) ^ ((j & 7) << 4);
  const __bf16* ksrc = kbf  + (size_t)j*(NKV_*HD_) + kvh*HD_ + c0;
  const __bf16* vsrc = vtbf + (size_t)(kvh*64 + j)*S_ + c0;

  // ---- Q fragments for both tiles ----
  bf16x8 qfA0, qfA1, qfB0, qfB1;
  {
    const __bf16* qa = qbf + (size_t)(qbA*64 + w*16 + l15)*D_ + h*HD_ + lg*8;
    qfA0 = *reinterpret_cast<const bf16x8*>(qa);
    qfA1 = *reinterpret_cast<const bf16x8*>(qa + 32);
    const __bf16* qb = qbf + (size_t)(qbB*64 + w*16 + l15)*D_ + h*HD_ + lg*8;
    qfB0 = *reinterpret_cast<const bf16x8*>(qb);
    qfB1 = *reinterpret_cast<const bf16x8*>(qb + 32);
  }

  f32x4 oA[4], oB[4];
#pragma unroll
  for (int nb = 0; nb < 4; ++nb) {
    oA[nb] = f32x4{0.f, 0.f, 0.f, 0.f};
    oB[nb] = f32x4{0.f, 0.f, 0.f, 0.f};
  }
  float mA[4] = {-1e30f, -1e30f, -1e30f, -1e30f};
  float lA[4] = {0.f, 0.f, 0.f, 0.f};
  float mB[4] = {-1e30f, -1e30f, -1e30f, -1e30f};
  float lB[4] = {0.f, 0.f, 0.f, 0.f};

  // prologue: prefetch tile 0
  uint4 kr0 = reinterpret_cast<const uint4*>(ksrc)[0];
  uint4 kr1 = reinterpret_cast<const uint4*>(ksrc + 8)[0];
  uint4 vr0 = reinterpret_cast<const uint4*>(vsrc)[0];
  uint4 vr1 = reinterpret_cast<const uint4*>(vsrc + 8)[0];

  for (int kt = 0; kt <= nkt; ++kt) {
    __syncthreads();
    *reinterpret_cast<uint4*>(kld + b0) = kr0;
    *reinterpret_cast<uint4*>(kld + b1) = kr1;
    *reinterpret_cast<uint4*>(vtl + b0) = vr0;
    *reinterpret_cast<uint4*>(vtl + b1) = vr1;
    __syncthreads();

    if (kt < nkt) {   // T14: next tile's loads drain under this tile's compute
      const __bf16* kn = ksrc + (size_t)(kt + 1)*64*(NKV_*HD_);
      const __bf16* vn = vsrc + (size_t)(kt + 1)*64;
      kr0 = reinterpret_cast<const uint4*>(kn)[0];
      kr1 = reinterpret_cast<const uint4*>(kn + 8)[0];
      vr0 = reinterpret_cast<const uint4*>(vn)[0];
      vr1 = reinterpret_cast<const uint4*>(vn + 8)[0];
    }

    // ---- tile B (always active) ----
    {
      f32x4 s_[4];
      qk_tile(kld, qfB0, qfB1, s_, l15, lg);
      if (kt == qbB) {
#pragma unroll
        for (int nb = 0; nb < 4; ++nb)
#pragma unroll
          for (int r = 0; r < 4; ++r)
            if (nb*16 + l15 > w*16 + lg*4 + r) s_[nb][r] = -1e30f;
      }
      softmax_pv(s_, mB, lB, oB, pld[w], vtl, l15, lg);
    }
    // ---- tile A (active while kt <= qbA) ----
    if (kt <= qbA) {
      f32x4 s_[4];
      qk_tile(kld, qfA0, qfA1, s_, l15, lg);
      if (kt == qbA) {
#pragma unroll
        for (int nb = 0; nb < 4; ++nb)
#pragma unroll
          for (int r = 0; r < 4; ++r)
            if (nb*16 + l15 > w*16 + lg*4 + r) s_[nb][r] = -1e30f;
      }
      softmax_pv(s_, mA, lA, oA, pld[w], vtl, l15, lg);
    }
  }

  // ---- epilogue (bf16 — only consumed by the wo GEMM) ----
#pragma unroll
  for (int nb = 0; nb < 4; ++nb) {
#pragma unroll
    for (int r = 0; r < 4; ++r) {
      const int rowA = qbA*64 + w*16 + lg*4 + r;
      const int rowB = qbB*64 + w*16 + lg*4 + r;
      ypre[(size_t)rowA*D_ + h*HD_ + nb*16 + l15] = (__bf16)(oA[nb][r] / lA[r]);
      ypre[(size_t)rowB*D_ + h*HD_ + nb*16 + l15] = (__bf16)(oB[nb][r] / lB[r]);
    }
  }
}

// --------------------------------------------------------------------------
extern "C" void kernel_launch(void* const* d_in, const int* in_sizes, int n_in,
                              void* d_out, int out_size, void* d_ws, size_t ws_size,
                              hipStream_t stream) {
  (void)in_sizes; (void)n_in; (void)out_size;
  const float* hs   = (const float*)d_in[0];
  const float* fcos = (const float*)d_in[1];
  const float* fsin = (const float*)d_in[2];
  // d_in[3] = atten_mask (pure causal; implemented directly)
  const float* wq = (const float*)d_in[4];
  const float* wk = (const float*)d_in[5];
  const float* wv = (const float*)d_in[6];
  const float* wo = (const float*)d_in[7];
  const float* qw = (const float*)d_in[8];
  const float* kw = (const float*)d_in[9];

  float* out = (float*)d_out;
  float* y   = out;                 // 2048*2048
  float* khT = out + 4194304;       // 32*64*2048
  float* vh  = out + 8388608;       // 32*2048*64

  // bf16 scratch parked in dead d_out regions:
  //  y region   (16MB): qbf 8MB | kbf 2MB | vtbf 2MB    (dead once wo GEMM runs)
  //  khT region (16MB): hs_bf 8MB | wq_bf 8MB           (dead after QKV GEMM)
  //  vh region  (16MB): wk_bf 2MB | wv_bf 2MB           (dead after QKV GEMM)
  __bf16* qbf   = (__bf16*)y;
  __bf16* kbf   = (__bf16*)((char*)y + 8*1024*1024);
  __bf16* vtbf  = (__bf16*)((char*)y + 10*1024*1024);
  __bf16* hs_bf = (__bf16*)khT;
  __bf16* wq_bf = (__bf16*)((char*)khT + 8*1024*1024);
  __bf16* wk_bf = (__bf16*)vh;
  __bf16* wv_bf = (__bf16*)((char*)vh + 2*1024*1024);

  const size_t need = (size_t)40 * 1024 * 1024;
  if (ws_size < need) return;
  char* ws = (char*)d_ws;
  float*  qp      = (float*)(ws);                    // 16MB: S x 2048 f32
  float*  kp      = (float*)(ws + 16*1024*1024);     //  4MB: S x 512 f32
  float*  vp      = (float*)(ws + 20*1024*1024);     //  4MB: S x 512 f32
  __bf16* ypre_bf = (__bf16*)(ws + 24*1024*1024);    //  8MB: S x 2048 bf16
  __bf16* wo_bf   = (__bf16*)(ws + 32*1024*1024);    //  8MB

  // convert fp32 inputs to bf16
  cvt_f32_bf16<<<4096, 256, 0, stream>>>(hs, hs_bf, 1048576);
  cvt_f32_bf16<<<4096, 256, 0, stream>>>(wq, wq_bf, 1048576);
  cvt_f32_bf16<<<1024, 256, 0, stream>>>(wk, wk_bf, 262144);
  cvt_f32_bf16<<<1024, 256, 0, stream>>>(wv, wv_bf, 262144);
  cvt_f32_bf16<<<4096, 256, 0, stream>>>(wo, wo_bf, 1048576);

  // fused Q/K/V projections (bf16 MFMA, fp32 out)
  gemm_qkv<<<dim3(24, 16), 256, 0, stream>>>(hs_bf, wq_bf, wk_bf, wv_bf, qp, kp, vp);

  rope_norm_q<<<16384, 256, 0, stream>>>(qp, fcos, fsin, qw, qbf);
  rope_norm_k<<< 4096, 256, 0, stream>>>(kp, fcos, fsin, kw, kbf);

  transpose_khT<<<dim3(32, 8), 256, 0, stream>>>(kp, khT);   // khT scratch dead now
  transpose_v<<<dim3(32, 8), 256, 0, stream>>>(vp, vh, vtbf);// vh scratch dead now

  // paired q-tiles: grid (16 pairs, 32 heads), each block = 33 tile units
  flash_attn_mfma<<<dim3(16, 32), 256, 0, stream>>>(qbf, kbf, vtbf, ypre_bf);

  // output projection (y region scratch dead now)
  gemm_wo<<<dim3(16, 16), 256, 0, stream>>>(ypre_bf, wo_bf, y);
}